// Round 9
// baseline (1509.463 us; speedup 1.0000x reference)
//
#include <hip/hip_runtime.h>
#include <hip/hip_bf16.h>
#include <math.h>

// B=16384, NB=8, NA=16, D=128, IN_DIM=2304, QK_DIM=384, V_DIM=128
static constexpr size_t OFF_ATT = 262144;      // attended_sf (33,554,432 f32)
static constexpr size_t OFF_LOG = 33816576;    // attn_logits
static constexpr size_t OFF_W   = 33947648;    // attention_weights
static constexpr size_t OFF_KM  = 34078720;    // keys_masked
static constexpr size_t OFF_VM  = 84410368;    // values_masked (268,435,456 f32)
static constexpr size_t OFF_SIM = 352845824;   // sim (7)

typedef short bf16x8 __attribute__((ext_vector_type(8)));
typedef float f32x4 __attribute__((ext_vector_type(4)));

__device__ inline unsigned short f2bf(float f) {
  union { float f; unsigned u; } x; x.f = f;
  unsigned r = x.u + 0x7FFFu + ((x.u >> 16) & 1u);  // RNE
  return (unsigned short)(r >> 16);
}
__device__ inline float bf2f(unsigned short v) {
  union { unsigned u; float f; } x; x.u = ((unsigned)v) << 16; return x.f;
}

__device__ inline float wave_sum(float v) {
#pragma unroll
  for (int o = 32; o > 0; o >>= 1) v += __shfl_xor(v, o, 64);
  return v;
}

// One wave per (b,n) row: inverse L2 norm of task rows. Also zero sim slots.
__global__ void norm_kernel(const float* __restrict__ task, float* __restrict__ invn,
                            float* __restrict__ simo) {
  int idx = blockIdx.x * 4 + (threadIdx.x >> 6);
  int lane = threadIdx.x & 63;
  float t0 = task[(size_t)idx * 128 + lane];
  float t1 = task[(size_t)idx * 128 + 64 + lane];
  float s = wave_sum(t0 * t0 + t1 * t1);
  if (lane == 0) invn[idx] = rsqrtf(s);
  if (blockIdx.x == 0 && threadIdx.x < 7) simo[threadIdx.x] = 0.0f;
}

// Tiled transpose+cvt: WT[n][k] = bf16(W[k][n]). 64x64 tiles, coalesced both sides.
__global__ void wprep_t(const float* __restrict__ W, unsigned short* __restrict__ WT,
                        int K, int N) {
  int ntn = N >> 6;
  int kt = blockIdx.x / ntn, nt = blockIdx.x % ntn;
  int k0 = kt * 64, n0 = nt * 64;
  __shared__ float t[64][65];
  int tid = threadIdx.x;
  int r = tid >> 2, c0 = (tid & 3) * 16;
#pragma unroll
  for (int q = 0; q < 4; ++q) {
    float4 v = *(const float4*)(W + (size_t)(k0 + r) * N + n0 + c0 + q * 4);
    t[r][c0 + q * 4 + 0] = v.x; t[r][c0 + q * 4 + 1] = v.y;
    t[r][c0 + q * 4 + 2] = v.z; t[r][c0 + q * 4 + 3] = v.w;
  }
  __syncthreads();
  int n = tid >> 2, kc0 = (tid & 3) * 16;
#pragma unroll
  for (int q = 0; q < 4; ++q) {
    int kc = kc0 + q * 4;
    ushort4 o = make_ushort4(f2bf(t[kc + 0][n]), f2bf(t[kc + 1][n]),
                             f2bf(t[kc + 2][n]), f2bf(t[kc + 3][n]));
    *(ushort4*)(WT + (size_t)(n0 + n) * K + k0 + kc) = o;
  }
}

// ============ fused keys GEMM + A-build + sim + sfbf/qbf byproducts ============
// 128x128 tile over M=131072, N=384 (nt 0..2), K=2304 (72 steps of 32).
// A: f32 sources -> regs (coalesced: thread=(row-chunk,col4)) -> bf16 -> LDS[128][40].
// B: global_load_lds 16B, linear [128][32] + XOR involution swizzle (round-8).
// nt==(kt%3) block writes that K-tile's bf16 as packed sfbf/qbf; nt==0 accumulates sim
// by re-reading the staged LDS tile (consecutive rows adjacent, no scatter).
__global__ __launch_bounds__(256) void keys_build(
    const float* __restrict__ basis, const float* __restrict__ sf,
    const float* __restrict__ task, const float* __restrict__ invn,
    const unsigned short* __restrict__ WkT, const float* __restrict__ bias,
    const float* __restrict__ mask, float* __restrict__ km,
    unsigned short* __restrict__ sfbf, unsigned short* __restrict__ qbf,
    float* __restrict__ simo) {
  __shared__ unsigned short As[2 * 5120];  // [2][128][40] bf16
  __shared__ unsigned short Bs[2 * 4096];  // [2][128][32] bf16
  int bid = blockIdx.x;
  int swz = (bid & 7) * 384 + (bid >> 3);
  int mt = swz / 3, nt = swz - mt * 3;
  int tid = threadIdx.x;
  int wave = tid >> 6, lane = tid & 63;
  int wr = wave >> 1, wc = wave & 1;
  int m0g = mt * 128, n0g = nt * 128;
  int la = lane & 15, lkq = lane >> 4;
  int sl = ((lkq ^ ((la >> 1) & 3))) * 8;  // swizzled B k-slot for reads

  // B staging (pre-swizzled global source, linear LDS dest)
  int c_lo = wave * 128 + lane;
  int brow0 = c_lo >> 2, bkc0 = ((c_lo & 3) ^ ((brow0 >> 1) & 3)) * 8;
  int c_hi = c_lo + 64;
  int brow1 = c_hi >> 2, bkc1 = ((c_hi & 3) ^ ((brow1 >> 1) & 3)) * 8;
  const unsigned short* bg0 = WkT + (size_t)(n0g + brow0) * 2304 + bkc0;
  const unsigned short* bg1 = WkT + (size_t)(n0g + brow1) * 2304 + bkc1;
  int ldsB0 = wave * 1024, ldsB1 = ldsB0 + 512;

#define STAGE_B(ks, cb)                                                        \
  do {                                                                         \
    __builtin_amdgcn_global_load_lds(                                          \
        (const __attribute__((address_space(1))) void*)(bg0 + (ks) * 32),      \
        (__attribute__((address_space(3))) void*)(Bs + (cb) * 4096 + ldsB0),   \
        16, 0, 0);                                                             \
    __builtin_amdgcn_global_load_lds(                                          \
        (const __attribute__((address_space(1))) void*)(bg1 + (ks) * 32),      \
        (__attribute__((address_space(3))) void*)(Bs + (cb) * 4096 + ldsB1),   \
        16, 0, 0);                                                             \
  } while (0)

  // A staging mapping: thread -> (rows rbase+32q, float4 col c4); 8 lanes = 128B run
  int rbase = tid >> 3, c4 = tid & 7;
  float ivq[4];
#pragma unroll
  for (int q = 0; q < 4; ++q) ivq[q] = invn[m0g + rbase + 32 * q];
  bool qrow = ((rbase & 7) == 0);
  bool simblk = (nt == 0);

  float4 av[4];

  auto LOADA = [&](int k0) {
#pragma unroll
    for (int q = 0; q < 4; ++q) {
      size_t R = (size_t)(m0g + rbase + 32 * q);
      int k = k0 + c4 * 4;
      const float* p;
      if (k0 < 128)       p = basis + R * 128 + k;
      else if (k0 < 2176) p = sf + R * 2048 + (k - 128);
      else                p = task + R * 128 + (k - 2176);
      float4 x = *(const float4*)p;
      if (k0 >= 2176) { x.x *= ivq[q]; x.y *= ivq[q]; x.z *= ivq[q]; x.w *= ivq[q]; }
      av[q] = x;
    }
  };

  // cvt + LDS write; byproduct global writes for tile kt when nt==kt%3
  auto CVTW = [&](int cb, int kt) {
    unsigned short* aL = As + cb * 5120;
    bool wr_this = (nt == (kt % 3));
    int k0 = kt * 32;
#pragma unroll
    for (int q = 0; q < 4; ++q) {
      int row = rbase + 32 * q;
      ushort4 o = make_ushort4(f2bf(av[q].x), f2bf(av[q].y), f2bf(av[q].z), f2bf(av[q].w));
      *(ushort4*)(aL + row * 40 + c4 * 4) = o;
      if (wr_this) {
        size_t R = (size_t)(m0g + row);
        int k = k0 + c4 * 4;
        if (k0 >= 128 && k0 < 2176)
          *(ushort4*)(sfbf + R * 2048 + (k - 128)) = o;
        if (qrow)
          *(ushort4*)(qbf + (R >> 3) * 2304 + k) = o;
      }
    }
  };

  f32x4 acc[4][4];
#pragma unroll
  for (int i = 0; i < 4; ++i)
#pragma unroll
    for (int j = 0; j < 4; ++j) acc[i][j] = (f32x4)(0.f);

  float sa = 0.f;
  int pr = tid >> 1, hh = tid & 1;
  bool prok = ((pr & 7) != 7);

  // prologue: tile 0
  LOADA(0);
  STAGE_B(0, 0);
  CVTW(0, 0);
  __syncthreads();

  int cur = 0;
  for (int ks = 0; ks < 72; ++ks) {
    if (ks < 71) {
      LOADA((ks + 1) * 32);        // f32 loads overlap MFMA below (reg dep defers wait)
      STAGE_B(ks + 1, cur ^ 1);
    }
    {
      const unsigned short* aL = As + cur * 5120;
      const unsigned short* bL = Bs + cur * 4096;
      bf16x8 af[4], bfr[4];
#pragma unroll
      for (int mi = 0; mi < 4; ++mi)
        af[mi] = *(const bf16x8*)(aL + (wr * 64 + mi * 16 + la) * 40 + lkq * 8);
#pragma unroll
      for (int ni = 0; ni < 4; ++ni)
        bfr[ni] = *(const bf16x8*)(bL + (wc * 64 + ni * 16 + la) * 32 + sl);
#pragma unroll
      for (int mi = 0; mi < 4; ++mi)
#pragma unroll
        for (int ni = 0; ni < 4; ++ni)
          acc[mi][ni] = __builtin_amdgcn_mfma_f32_16x16x32_bf16(af[mi], bfr[ni], acc[mi][ni], 0, 0, 0);
    }
    if (simblk && prok) {  // sim: consecutive-row diffs from the staged tile
      const unsigned short* a0 = As + cur * 5120 + pr * 40 + hh * 16;
      bf16x8 x0 = *(const bf16x8*)(a0);
      bf16x8 x1 = *(const bf16x8*)(a0 + 8);
      bf16x8 y0 = *(const bf16x8*)(a0 + 40);
      bf16x8 y1 = *(const bf16x8*)(a0 + 48);
#pragma unroll
      for (int j = 0; j < 8; ++j) {
        float d0 = bf2f((unsigned short)x0[j]) - bf2f((unsigned short)y0[j]);
        sa = fmaf(d0, d0, sa);
        float d1 = bf2f((unsigned short)x1[j]) - bf2f((unsigned short)y1[j]);
        sa = fmaf(d1, d1, sa);
      }
    }
    if (ks < 71) CVTW(cur ^ 1, ks + 1);
    __syncthreads();
    cur ^= 1;
  }
#undef STAGE_B

  // C epilogue: km = (acc + bk) * mask_rep
  int rq = lane >> 4;
#pragma unroll
  for (int mi = 0; mi < 4; ++mi) {
#pragma unroll
    for (int ni = 0; ni < 4; ++ni) {
      int colg = n0g + wc * 64 + ni * 16 + la;
#pragma unroll
      for (int j = 0; j < 4; ++j) {
        int rowg = m0g + wr * 64 + mi * 16 + rq * 4 + j;
        float v = (acc[mi][ni][j] + bias[colg]) * mask[(size_t)rowg * 128 + (unsigned)colg / 3u];
        km[(size_t)rowg * 384 + colg] = v;
      }
    }
  }

  // sim epilogue (nt==0): combine col-halves, one atomicAdd per (b_local, n)
  if (simblk) {
    float* sarr = (float*)Bs;  // LDS free after final loop barrier
    sarr[tid] = sa;
    __syncthreads();
    if (hh == 0 && prok) {
      float s = sarr[tid] + sarr[tid + 1];
      atomicAdd(&simo[pr & 7], expf(-0.5f * s) * (1.0f / 16384.0f));
    }
  }
}

// One block (576 thr) per b (FALLBACK path only).
__global__ __launch_bounds__(576) void abuild_sim(const float* __restrict__ basis,
                                                  const float* __restrict__ sf,
                                                  const float* __restrict__ task,
                                                  const float* __restrict__ invn,
                                                  unsigned short* __restrict__ Abf,
                                                  float* __restrict__ simo) {
  int b = blockIdx.x;
  int f = threadIdx.x;  // 0..575
  size_t row0 = (size_t)b * 8;
  float4 v[8];
#pragma unroll
  for (int n = 0; n < 8; ++n) {
    size_t row = row0 + n;
    float4 x;
    if (f < 32)       x = *(const float4*)(basis + row * 128 + f * 4);
    else if (f < 544) x = *(const float4*)(sf + row * 2048 + (f - 32) * 4);
    else {
      x = *(const float4*)(task + row * 128 + (f - 544) * 4);
      float s = invn[row];
      x.x *= s; x.y *= s; x.z *= s; x.w *= s;
    }
    v[n] = x;
    ushort4 o = make_ushort4(f2bf(x.x), f2bf(x.y), f2bf(x.z), f2bf(x.w));
    *(ushort4*)(Abf + row * 2304 + f * 4) = o;
  }
  float s7[7];
#pragma unroll
  for (int n = 1; n < 8; ++n) {
    float dx = v[n].x - v[n - 1].x, dy = v[n].y - v[n - 1].y;
    float dz = v[n].z - v[n - 1].z, dw = v[n].w - v[n - 1].w;
    s7[n - 1] = dx * dx + dy * dy + dz * dz + dw * dw;
  }
  __shared__ float red[9][7];
  int wid = threadIdx.x >> 6, lane = threadIdx.x & 63;
#pragma unroll
  for (int i = 0; i < 7; ++i) {
    float p = wave_sum(s7[i]);
    if (lane == 0) red[wid][i] = p;
  }
  __syncthreads();
  if (threadIdx.x < 7) {
    float s = 0.f;
#pragma unroll
    for (int w = 0; w < 9; ++w) s += red[w][threadIdx.x];
    atomicAdd(&simo[threadIdx.x], expf(-0.5f * s) * (1.0f / 16384.0f));
  }
}

// MFMA GEMM, out[M x 384] = A rows @ WT^T. MODE 0: keys from Abf (+bias,*mask,
// fallback). MODE 1: query from packed qbf. MODE 2: query from Abf stride-8 (fallback).
template <int MODE>
__global__ __launch_bounds__(256) void qk_gemm(const unsigned short* __restrict__ Abf,
                                               const unsigned short* __restrict__ WT,
                                               const float* __restrict__ bias,
                                               const float* __restrict__ mask,
                                               float* __restrict__ outp) {
  __shared__ unsigned short As[2 * 4096];
  __shared__ unsigned short Bs[2 * 4096];
  int nwg = gridDim.x, per = nwg >> 3;
  int bid = blockIdx.x;
  int swz = (bid & 7) * per + (bid >> 3);
  int mt = swz / 3, nt = swz - mt * 3;
  int tid = threadIdx.x;
  int wave = tid >> 6, lane = tid & 63;
  int wr = wave >> 1, wc = wave & 1;
  int m0g = mt * 128, n0g = nt * 128;

  int c_lo = wave * 128 + lane;
  int row_q0 = c_lo >> 2, kc_q0 = ((c_lo & 3) ^ ((row_q0 >> 1) & 3)) * 8;
  int c_hi = c_lo + 64;
  int row_q1 = c_hi >> 2, kc_q1 = ((c_hi & 3) ^ ((row_q1 >> 1) & 3)) * 8;
  size_t ga_q0 = (MODE == 2) ? (size_t)(m0g + row_q0) * 8 : (size_t)(m0g + row_q0);
  size_t ga_q1 = (MODE == 2) ? (size_t)(m0g + row_q1) * 8 : (size_t)(m0g + row_q1);
  const unsigned short* ag0 = Abf + ga_q0 * 2304 + kc_q0;
  const unsigned short* ag1 = Abf + ga_q1 * 2304 + kc_q1;
  const unsigned short* bg0 = WT + (size_t)(n0g + row_q0) * 2304 + kc_q0;
  const unsigned short* bg1 = WT + (size_t)(n0g + row_q1) * 2304 + kc_q1;
  int ldsoff0 = wave * 1024;
  int ldsoff1 = ldsoff0 + 512;

#define STAGE(ks, cur)                                                                   \
  do {                                                                                   \
    int _k0 = (ks) * 32;                                                                 \
    unsigned short* _a = As + (cur) * 4096;                                              \
    unsigned short* _b = Bs + (cur) * 4096;                                              \
    __builtin_amdgcn_global_load_lds(                                                    \
        (const __attribute__((address_space(1))) void*)(ag0 + _k0),                      \
        (__attribute__((address_space(3))) void*)(_a + ldsoff0), 16, 0, 0);              \
    __builtin_amdgcn_global_load_lds(                                                    \
        (const __attribute__((address_space(1))) void*)(ag1 + _k0),                      \
        (__attribute__((address_space(3))) void*)(_a + ldsoff1), 16, 0, 0);              \
    __builtin_amdgcn_global_load_lds(                                                    \
        (const __attribute__((address_space(1))) void*)(bg0 + _k0),                      \
        (__attribute__((address_space(3))) void*)(_b + ldsoff0), 16, 0, 0);              \
    __builtin_amdgcn_global_load_lds(                                                    \
        (const __attribute__((address_space(1))) void*)(bg1 + _k0),                      \
        (__attribute__((address_space(3))) void*)(_b + ldsoff1), 16, 0, 0);              \
  } while (0)

  f32x4 acc[4][4];
#pragma unroll
  for (int i = 0; i < 4; ++i)
#pragma unroll
    for (int j = 0; j < 4; ++j) acc[i][j] = (f32x4)(0.f);

  int la = lane & 15;
  int sl = (((lane >> 4) ^ ((la >> 1) & 3))) * 8;

  STAGE(0, 0);
  __syncthreads();
  int cur = 0;
  for (int ks = 0; ks < 72; ++ks) {
    if (ks < 71) STAGE(ks + 1, cur ^ 1);
    const unsigned short* aL = As + cur * 4096;
    const unsigned short* bL = Bs + cur * 4096;
    bf16x8 af[4], bf[4];
#pragma unroll
    for (int mi = 0; mi < 4; ++mi)
      af[mi] = *(const bf16x8*)(aL + (wr * 64 + mi * 16 + la) * 32 + sl);
#pragma unroll
    for (int ni = 0; ni < 4; ++ni)
      bf[ni] = *(const bf16x8*)(bL + (wc * 64 + ni * 16 + la) * 32 + sl);
#pragma unroll
    for (int mi = 0; mi < 4; ++mi)
#pragma unroll
      for (int ni = 0; ni < 4; ++ni)
        acc[mi][ni] = __builtin_amdgcn_mfma_f32_16x16x32_bf16(af[mi], bf[ni], acc[mi][ni], 0, 0, 0);
    __syncthreads();
    cur ^= 1;
  }
#undef STAGE

  int rq = lane >> 4;
#pragma unroll
  for (int mi = 0; mi < 4; ++mi) {
#pragma unroll
    for (int ni = 0; ni < 4; ++ni) {
      int colg = nt * 128 + wc * 64 + ni * 16 + la;
#pragma unroll
      for (int j = 0; j < 4; ++j) {
        int rowg = mt * 128 + wr * 64 + mi * 16 + rq * 4 + j;
        float v = acc[mi][ni][j];
        if (MODE == 0)
          v = (v + bias[colg]) * mask[(size_t)rowg * 128 + (unsigned)colg / 3u];
        outp[(size_t)rowg * 384 + colg] = v;
      }
    }
  }
}

// 4 b per block, one wave per b: logits + where(==0) + softmax. Zero LDS/barriers.
__global__ __launch_bounds__(256) void attn_kernel4(const float* __restrict__ query,
                                                    const float* __restrict__ km,
                                                    float* __restrict__ logits,
                                                    float* __restrict__ wts) {
  int w = threadIdx.x >> 6, lane = threadIdx.x & 63;
  int b = blockIdx.x * 4 + w;
  float q[6];
#pragma unroll
  for (int j = 0; j < 6; ++j) q[j] = query[(size_t)b * 384 + lane + 64 * j];
  float lg[8];
#pragma unroll
  for (int n = 0; n < 8; ++n) {
    const float* kr = km + ((size_t)b * 8 + n) * 384;
    float p = 0.f;
#pragma unroll
    for (int j = 0; j < 6; ++j) p = fmaf(q[j], kr[lane + 64 * j], p);
    p = wave_sum(p);
    float l = p * 0.08838834764831845f;  // 1/sqrt(128)
    lg[n] = (l == 0.0f) ? -1e9f : l;
  }
  float m = lg[0];
#pragma unroll
  for (int i = 1; i < 8; ++i) m = fmaxf(m, lg[i]);
  float ex[8], s = 0.f;
#pragma unroll
  for (int i = 0; i < 8; ++i) { ex[i] = expf(lg[i] - m); s += ex[i]; }
  float inv = 1.0f / s;
  if (lane < 8) {
    float lv = lg[0], ev = ex[0];
#pragma unroll
    for (int i = 1; i < 8; ++i)
      if (lane == i) { lv = lg[i]; ev = ex[i]; }
    logits[(size_t)b * 8 + lane] = lv;
    wts[(size_t)b * 8 + lane] = ev * inv;
  }
}

// Values GEMM + fused attend + q1. One block = one b.
// ABF=1: A from packed sfbf (bf16 [2M][128]) via global_load_lds + swizzle; B from WvT.
// ABF=0: A from sf f32 (inline cvt), B transposed in-block from Wv f32 (fallback).
template <int ABF>
__global__ __launch_bounds__(256) void v_gemm_attend(const float* __restrict__ sf,
                                                     const unsigned short* __restrict__ sfbf,
                                                     const float* __restrict__ Wv,
                                                     const unsigned short* __restrict__ WvT,
                                                     const float* __restrict__ bv,
                                                     const float* __restrict__ wts,
                                                     const float* __restrict__ task,
                                                     float* __restrict__ vm,
                                                     float* __restrict__ att,
                                                     float* __restrict__ q1) {
  __shared__ unsigned short As[2 * 4096];
  __shared__ unsigned short Bs[128 * 136];
  float* attL = (float*)As;
  int bid = blockIdx.x;
  int swz = (bid & 7) * 2048 + (bid >> 3);
  int b = swz;
  size_t m0 = (size_t)swz * 128;
  int tid = threadIdx.x;
  int wave = tid >> 6, lane = tid & 63;
  int wr = wave >> 1, wc = wave & 1;
  int r = tid >> 1, h = tid & 1;
  int la = lane & 15, lkq = lane >> 4;
  int sl = ((lkq ^ ((la >> 1) & 3))) * 8;

  if (ABF) {
#pragma unroll
    for (int q = 0; q < 8; ++q) {
      bf16x8 v = *(const bf16x8*)(WvT + (size_t)r * 128 + h * 64 + q * 8);
      *(bf16x8*)(Bs + r * 136 + h * 64 + q * 8) = v;
    }
  } else {
#pragma unroll
    for (int q = 0; q < 16; ++q) {
      int flat = q * 256 + tid;
      int k = flat >> 5;
      int n4 = (flat & 31) * 4;
      float4 v = *(const float4*)(Wv + (size_t)k * 128 + n4);
      Bs[(n4 + 0) * 136 + k] = f2bf(v.x);
      Bs[(n4 + 1) * 136 + k] = f2bf(v.y);
      Bs[(n4 + 2) * 136 + k] = f2bf(v.z);
      Bs[(n4 + 3) * 136 + k] = f2bf(v.w);
    }
  }

  const unsigned short *ap0 = nullptr, *ap1 = nullptr;
  int ldsA0 = wave * 1024, ldsA1 = ldsA0 + 512;
  if (ABF) {
    int p0 = wave * 128 + lane;
    int tr0 = p0 >> 2, ds0 = (p0 & 3) ^ ((tr0 >> 1) & 3);
    int p1 = p0 + 64;
    int tr1 = p1 >> 2, ds1 = (p1 & 3) ^ ((tr1 >> 1) & 3);
    ap0 = sfbf + ((size_t)b * 8 + (tr0 >> 4)) * 2048 + (tr0 & 15) * 128 + ds0 * 8;
    ap1 = sfbf + ((size_t)b * 8 + (tr1 >> 4)) * 2048 + (tr1 & 15) * 128 + ds1 * 8;
    __builtin_amdgcn_global_load_lds(
        (const __attribute__((address_space(1))) void*)(ap0),
        (__attribute__((address_space(3))) void*)(As + ldsA0), 16, 0, 0);
    __builtin_amdgcn_global_load_lds(
        (const __attribute__((address_space(1))) void*)(ap1),
        (__attribute__((address_space(3))) void*)(As + ldsA1), 16, 0, 0);
  }

  f32x4 acc[4][4];
#pragma unroll
  for (int i = 0; i < 4; ++i)
#pragma unroll
    for (int j = 0; j < 4; ++j) acc[i][j] = (f32x4)(0.f);

  if (ABF) __syncthreads();

  int cur = 0;
  for (int ks = 0; ks < 4; ++ks) {
    int k0 = ks * 32;
    if (ABF) {
      if (ks < 3) {
        __builtin_amdgcn_global_load_lds(
            (const __attribute__((address_space(1))) void*)(ap0 + k0 + 32),
            (__attribute__((address_space(3))) void*)(As + (cur ^ 1) * 4096 + ldsA0), 16, 0, 0);
        __builtin_amdgcn_global_load_lds(
            (const __attribute__((address_space(1))) void*)(ap1 + k0 + 32),
            (__attribute__((address_space(3))) void*)(As + (cur ^ 1) * 4096 + ldsA1), 16, 0, 0);
      }
    } else {
      const float* ap = sf + (m0 + r) * 128 + k0 + h * 16;
      float4 v0 = *(const float4*)(ap);
      float4 v1 = *(const float4*)(ap + 4);
      float4 v2 = *(const float4*)(ap + 8);
      float4 v3 = *(const float4*)(ap + 12);
      ushort4 p0 = make_ushort4(f2bf(v0.x), f2bf(v0.y), f2bf(v0.z), f2bf(v0.w));
      ushort4 p1 = make_ushort4(f2bf(v1.x), f2bf(v1.y), f2bf(v1.z), f2bf(v1.w));
      ushort4 p2 = make_ushort4(f2bf(v2.x), f2bf(v2.y), f2bf(v2.z), f2bf(v2.w));
      ushort4 p3 = make_ushort4(f2bf(v3.x), f2bf(v3.y), f2bf(v3.z), f2bf(v3.w));
      *(ushort4*)(As + r * 40 + h * 16)      = p0;
      *(ushort4*)(As + r * 40 + h * 16 + 4)  = p1;
      *(ushort4*)(As + r * 40 + h * 16 + 8)  = p2;
      *(ushort4*)(As + r * 40 + h * 16 + 12) = p3;
      __syncthreads();
    }
    const unsigned short* aL = ABF ? (As + cur * 4096) : As;
    bf16x8 af[4], bfr[4];
#pragma unroll
    for (int mi = 0; mi < 4; ++mi) {
      int rowl = wr * 64 + mi * 16 + la;
      af[mi] = ABF ? *(const bf16x8*)(aL + rowl * 32 + sl)
                   : *(const bf16x8*)(aL + rowl * 40 + lkq * 8);
    }
#pragma unroll
    for (int ni = 0; ni < 4; ++ni)
      bfr[ni] = *(const bf16x8*)(Bs + (wc * 64 + ni * 16 + la) * 136 + k0 + lkq * 8);
#pragma unroll
    for (int mi = 0; mi < 4; ++mi)
#pragma unroll
      for (int ni = 0; ni < 4; ++ni)
        acc[mi][ni] = __builtin_amdgcn_mfma_f32_16x16x32_bf16(af[mi], bfr[ni], acc[mi][ni], 0, 0, 0);
    __syncthreads();
    cur ^= 1;
  }

  float w4[4];
#pragma unroll
  for (int mi = 0; mi < 4; ++mi) w4[mi] = wts[(size_t)b * 8 + wr * 4 + mi];
  float pacc[4][4];
#pragma unroll
  for (int ni = 0; ni < 4; ++ni)
#pragma unroll
    for (int j = 0; j < 4; ++j) pacc[ni][j] = 0.f;
#pragma unroll
  for (int mi = 0; mi < 4; ++mi) {
#pragma unroll
    for (int ni = 0; ni < 4; ++ni) {
      int colg = wc * 64 + ni * 16 + la;
      float bb = bv[colg];
#pragma unroll
      for (int j = 0; j < 4; ++j) {
        size_t rowg = m0 + wr * 64 + mi * 16 + lkq * 4 + j;
        float v = acc[mi][ni][j] + bb;
        vm[rowg * 128 + colg] = v;
        pacc[ni][j] = fmaf(w4[mi], v, pacc[ni][j]);
      }
    }
  }
  if (wr == 0) {
#pragma unroll
    for (int ni = 0; ni < 4; ++ni)
#pragma unroll
      for (int j = 0; j < 4; ++j)
        attL[(lkq * 4 + j) * 132 + wc * 64 + ni * 16 + la] = pacc[ni][j];
  }
  __syncthreads();
  if (wr == 1) {
#pragma unroll
    for (int ni = 0; ni < 4; ++ni)
#pragma unroll
      for (int j = 0; j < 4; ++j)
        attL[(lkq * 4 + j) * 132 + wc * 64 + ni * 16 + la] += pacc[ni][j];
  }
  __syncthreads();
#pragma unroll
  for (int i = 0; i < 2; ++i) {
    int fidx = tid + i * 256;
    int a = fidx >> 5, c = (fidx & 31) * 4;
    f32x4 vv = *(const f32x4*)(attL + a * 132 + c);
    *(f32x4*)(att + (size_t)b * 2048 + a * 128 + c) = vv;
  }
  for (int j = wave; j < 16; j += 4) {
    float p = task[(size_t)b * 1024 + lane] * attL[j * 132 + lane]
            + task[(size_t)b * 1024 + 64 + lane] * attL[j * 132 + 64 + lane];
    p = wave_sum(p);
    if (lane == 0) q1[(size_t)b * 16 + j] = p;
  }
}

extern "C" void kernel_launch(void* const* d_in, const int* in_sizes, int n_in,
                              void* d_out, int out_size, void* d_ws, size_t ws_size,
                              hipStream_t stream) {
  const float* basis = (const float*)d_in[0];
  const float* sf    = (const float*)d_in[1];
  const float* task  = (const float*)d_in[2];
  const float* mask  = (const float*)d_in[3];
  const float* Wq    = (const float*)d_in[4];
  const float* Wk    = (const float*)d_in[5];
  const float* bk    = (const float*)d_in[6];
  const float* Wv    = (const float*)d_in[7];
  const float* bv    = (const float*)d_in[8];

  float* out  = (float*)d_out;
  float* q1   = out;
  float* att  = out + OFF_ATT;
  float* logi = out + OFF_LOG;
  float* wts  = out + OFF_W;
  float* km   = out + OFF_KM;
  float* vm   = out + OFF_VM;
  float* simo = out + OFF_SIM;

  // d_ws layout: sfbf | qbf | WkT | WqT | WvT | query | invn  (~642 MB, disjoint
  // from all outputs -> no stash-lifetime hazards).
  constexpr size_t O_SFBF = 0;
  constexpr size_t O_QBF  = 536870912ull;
  constexpr size_t O_WKT  = O_QBF + 75497472ull;
  constexpr size_t O_WQT  = O_WKT + 1769472ull;
  constexpr size_t O_WVT  = O_WQT + 1769472ull;
  constexpr size_t O_QRY  = O_WVT + 32768ull;
  constexpr size_t O_INV  = O_QRY + 25165824ull;
  constexpr size_t WS_NEED = O_INV + 524288ull;
  bool usews = ws_size >= WS_NEED;

  if (usews) {
    unsigned char* ws = (unsigned char*)d_ws;
    unsigned short* sfbf = (unsigned short*)(ws + O_SFBF);
    unsigned short* qbf  = (unsigned short*)(ws + O_QBF);
    unsigned short* WkT  = (unsigned short*)(ws + O_WKT);
    unsigned short* WqT  = (unsigned short*)(ws + O_WQT);
    unsigned short* WvT  = (unsigned short*)(ws + O_WVT);
    float* query = (float*)(ws + O_QRY);
    float* invn  = (float*)(ws + O_INV);

    norm_kernel<<<32768, 256, 0, stream>>>(task, invn, simo);
    wprep_t<<<216, 256, 0, stream>>>(Wk, WkT, 2304, 384);
    wprep_t<<<216, 256, 0, stream>>>(Wq, WqT, 2304, 384);
    wprep_t<<<4, 256, 0, stream>>>(Wv, WvT, 128, 128);
    // fused: keys GEMM + A-build + sim + sfbf/qbf byproducts
    keys_build<<<3072, 256, 0, stream>>>(basis, sf, task, invn, WkT, bk, mask,
                                         km, sfbf, qbf, simo);
    // query: M=16384 packed rows, N=384, K=2304
    qk_gemm<1><<<384, 256, 0, stream>>>(qbf, WqT, nullptr, nullptr, query);
    attn_kernel4<<<4096, 256, 0, stream>>>(query, km, logi, wts);
    // values GEMM + fused attend/q1 from packed sfbf
    v_gemm_attend<1><<<16384, 256, 0, stream>>>(sf, sfbf, Wv, WvT, bv, wts, task,
                                                vm, att, q1);
  } else {
    // fallback = round-8 pipeline with output-region stashes
    float* query = att;                                 // 6,291,456 f32
    float* invn  = att + 6291456;                       //   131,072 f32
    unsigned short* WkT = (unsigned short*)(att + 6422528);
    unsigned short* WqT = WkT + 884736;
    unsigned short* Abf = (unsigned short*)vm;          // 301,989,888 bf16

    norm_kernel<<<32768, 256, 0, stream>>>(task, invn, simo);
    wprep_t<<<216, 256, 0, stream>>>(Wk, WkT, 2304, 384);
    wprep_t<<<216, 256, 0, stream>>>(Wq, WqT, 2304, 384);
    abuild_sim<<<16384, 576, 0, stream>>>(basis, sf, task, invn, Abf, simo);
    qk_gemm<0><<<3072, 256, 0, stream>>>(Abf, WkT, bk, mask, km);
    qk_gemm<2><<<384, 256, 0, stream>>>(Abf, WqT, nullptr, nullptr, query);
    attn_kernel4<<<4096, 256, 0, stream>>>(query, km, logi, wts);
    v_gemm_attend<0><<<16384, 256, 0, stream>>>(sf, nullptr, Wv, nullptr, bv, wts,
                                                task, vm, att, q1);
  }
}

// Round 10
// 1398.141 us; speedup vs baseline: 1.0796x; 1.0796x over previous
//
#include <hip/hip_runtime.h>
#include <hip/hip_bf16.h>
#include <math.h>

// B=16384, NB=8, NA=16, D=128, IN_DIM=2304, QK_DIM=384, V_DIM=128
static constexpr size_t OFF_ATT = 262144;      // attended_sf (33,554,432 f32)
static constexpr size_t OFF_LOG = 33816576;    // attn_logits
static constexpr size_t OFF_W   = 33947648;    // attention_weights
static constexpr size_t OFF_KM  = 34078720;    // keys_masked
static constexpr size_t OFF_VM  = 84410368;    // values_masked (268,435,456 f32)
static constexpr size_t OFF_SIM = 352845824;   // sim (7)

typedef short bf16x8 __attribute__((ext_vector_type(8)));
typedef float f32x4 __attribute__((ext_vector_type(4)));

__device__ inline unsigned short f2bf(float f) {
  union { float f; unsigned u; } x; x.f = f;
  unsigned r = x.u + 0x7FFFu + ((x.u >> 16) & 1u);  // RNE
  return (unsigned short)(r >> 16);
}

__device__ inline float wave_sum(float v) {
#pragma unroll
  for (int o = 32; o > 0; o >>= 1) v += __shfl_xor(v, o, 64);
  return v;
}

// One wave per (b,n) row: inverse L2 norm of task rows. Also zero sim slots.
__global__ void norm_kernel(const float* __restrict__ task, float* __restrict__ invn,
                            float* __restrict__ simo) {
  int idx = blockIdx.x * 4 + (threadIdx.x >> 6);
  int lane = threadIdx.x & 63;
  float t0 = task[(size_t)idx * 128 + lane];
  float t1 = task[(size_t)idx * 128 + 64 + lane];
  float s = wave_sum(t0 * t0 + t1 * t1);
  if (lane == 0) invn[idx] = rsqrtf(s);
  if (blockIdx.x == 0 && threadIdx.x < 7) simo[threadIdx.x] = 0.0f;
}

// Tiled transpose+cvt: WT[n][k] = bf16(W[k][n]). 64x64 tiles, coalesced both sides.
__global__ void wprep_t(const float* __restrict__ W, unsigned short* __restrict__ WT,
                        int K, int N) {
  int ntn = N >> 6;
  int kt = blockIdx.x / ntn, nt = blockIdx.x % ntn;
  int k0 = kt * 64, n0 = nt * 64;
  __shared__ float t[64][65];
  int tid = threadIdx.x;
  int r = tid >> 2, c0 = (tid & 3) * 16;
#pragma unroll
  for (int q = 0; q < 4; ++q) {
    float4 v = *(const float4*)(W + (size_t)(k0 + r) * N + n0 + c0 + q * 4);
    t[r][c0 + q * 4 + 0] = v.x; t[r][c0 + q * 4 + 1] = v.y;
    t[r][c0 + q * 4 + 2] = v.z; t[r][c0 + q * 4 + 3] = v.w;
  }
  __syncthreads();
  int n = tid >> 2, kc0 = (tid & 3) * 16;
#pragma unroll
  for (int q = 0; q < 4; ++q) {
    int kc = kc0 + q * 4;
    ushort4 o = make_ushort4(f2bf(t[kc + 0][n]), f2bf(t[kc + 1][n]),
                             f2bf(t[kc + 2][n]), f2bf(t[kc + 3][n]));
    *(ushort4*)(WT + (size_t)(n0 + n) * K + k0 + kc) = o;
  }
}

// One block (576 thr) per b: thread owns one float4-chunk f of the 2304-row.
// Loads all 8 rows' chunks (independent), writes bf16 Abf, and accumulates the
// 7 consecutive-row squared-diff partials in registers.
__global__ __launch_bounds__(576) void abuild_sim(const float* __restrict__ basis,
                                                  const float* __restrict__ sf,
                                                  const float* __restrict__ task,
                                                  const float* __restrict__ invn,
                                                  unsigned short* __restrict__ Abf,
                                                  float* __restrict__ simo) {
  int b = blockIdx.x;
  int f = threadIdx.x;  // 0..575
  size_t row0 = (size_t)b * 8;
  float4 v[8];
#pragma unroll
  for (int n = 0; n < 8; ++n) {
    size_t row = row0 + n;
    float4 x;
    if (f < 32)       x = *(const float4*)(basis + row * 128 + f * 4);
    else if (f < 544) x = *(const float4*)(sf + row * 2048 + (f - 32) * 4);
    else {
      x = *(const float4*)(task + row * 128 + (f - 544) * 4);
      float s = invn[row];
      x.x *= s; x.y *= s; x.z *= s; x.w *= s;
    }
    v[n] = x;
    ushort4 o = make_ushort4(f2bf(x.x), f2bf(x.y), f2bf(x.z), f2bf(x.w));
    *(ushort4*)(Abf + row * 2304 + f * 4) = o;
  }
  float s7[7];
#pragma unroll
  for (int n = 1; n < 8; ++n) {
    float dx = v[n].x - v[n - 1].x, dy = v[n].y - v[n - 1].y;
    float dz = v[n].z - v[n - 1].z, dw = v[n].w - v[n - 1].w;
    s7[n - 1] = dx * dx + dy * dy + dz * dz + dw * dw;
  }
  __shared__ float red[9][7];
  int wid = threadIdx.x >> 6, lane = threadIdx.x & 63;
#pragma unroll
  for (int i = 0; i < 7; ++i) {
    float p = wave_sum(s7[i]);
    if (lane == 0) red[wid][i] = p;
  }
  __syncthreads();
  if (threadIdx.x < 7) {
    float s = 0.f;
#pragma unroll
    for (int w = 0; w < 9; ++w) s += red[w][threadIdx.x];
    atomicAdd(&simo[threadIdx.x], expf(-0.5f * s) * (1.0f / 16384.0f));
  }
}

// Combined keys+query MFMA GEMM: blocks [0,3072) do keys (M=131072, +bias,*mask),
// blocks [3072,3456) do query (M=16384, A rows stride 8 in Abf). 128x128 tile,
// BK=32, 4 waves. Triple-buffered global_load_lds staging with COUNTED vmcnt:
// prefetch distance 2, raw s_barrier + s_waitcnt vmcnt(4) so the newest stage's
// 4 loads stay in flight across the barrier (kills the vmcnt(0) drain stall).
// XOR involution swizzle on k-slots (round-8) retained.
__global__ __launch_bounds__(256) void qk2(const unsigned short* __restrict__ Abf,
                                           const unsigned short* __restrict__ WkT,
                                           const unsigned short* __restrict__ WqT,
                                           const float* __restrict__ bias,
                                           const float* __restrict__ mask,
                                           float* __restrict__ km,
                                           float* __restrict__ query) {
  __shared__ unsigned short As[3 * 4096];
  __shared__ unsigned short Bs[3 * 4096];
  int bid = blockIdx.x;
  bool isq = bid >= 3072;
  int mt, nt;
  const unsigned short* WT;
  float* outp;
  if (!isq) {
    int swz = (bid & 7) * 384 + (bid >> 3);
    mt = swz / 3; nt = swz - mt * 3;
    WT = WkT; outp = km;
  } else {
    int q = bid - 3072;
    int swz = (q & 7) * 48 + (q >> 3);
    mt = swz / 3; nt = swz - mt * 3;
    WT = WqT; outp = query;
  }
  int tid = threadIdx.x;
  int wave = tid >> 6, lane = tid & 63;
  int wr = wave >> 1, wc = wave & 1;
  int m0g = mt * 128, n0g = nt * 128;

  // staging geometry (r8): chunk c = wave*128 + lane (+64); row=c>>2;
  // global k-slot pre-swizzled by the involution slot^((row>>1)&3)
  int c_lo = wave * 128 + lane;
  int row_q0 = c_lo >> 2, kc_q0 = ((c_lo & 3) ^ ((row_q0 >> 1) & 3)) * 8;
  int c_hi = c_lo + 64;
  int row_q1 = c_hi >> 2, kc_q1 = ((c_hi & 3) ^ ((row_q1 >> 1) & 3)) * 8;
  size_t ga_q0 = isq ? (size_t)(m0g + row_q0) * 8 : (size_t)(m0g + row_q0);
  size_t ga_q1 = isq ? (size_t)(m0g + row_q1) * 8 : (size_t)(m0g + row_q1);
  const unsigned short* ag0 = Abf + ga_q0 * 2304 + kc_q0;
  const unsigned short* ag1 = Abf + ga_q1 * 2304 + kc_q1;
  const unsigned short* bg0 = WT + (size_t)(n0g + row_q0) * 2304 + kc_q0;
  const unsigned short* bg1 = WT + (size_t)(n0g + row_q1) * 2304 + kc_q1;
  int ldsoff0 = wave * 1024;  // elements; wave-uniform (HW adds lane*16B)
  int ldsoff1 = ldsoff0 + 512;

#define STAGE(ks, buf)                                                                   \
  do {                                                                                   \
    int _k0 = (ks) * 32;                                                                 \
    unsigned short* _a = As + (buf) * 4096;                                              \
    unsigned short* _b = Bs + (buf) * 4096;                                              \
    __builtin_amdgcn_global_load_lds(                                                    \
        (const __attribute__((address_space(1))) void*)(ag0 + _k0),                      \
        (__attribute__((address_space(3))) void*)(_a + ldsoff0), 16, 0, 0);              \
    __builtin_amdgcn_global_load_lds(                                                    \
        (const __attribute__((address_space(1))) void*)(ag1 + _k0),                      \
        (__attribute__((address_space(3))) void*)(_a + ldsoff1), 16, 0, 0);              \
    __builtin_amdgcn_global_load_lds(                                                    \
        (const __attribute__((address_space(1))) void*)(bg0 + _k0),                      \
        (__attribute__((address_space(3))) void*)(_b + ldsoff0), 16, 0, 0);              \
    __builtin_amdgcn_global_load_lds(                                                    \
        (const __attribute__((address_space(1))) void*)(bg1 + _k0),                      \
        (__attribute__((address_space(3))) void*)(_b + ldsoff1), 16, 0, 0);              \
  } while (0)

  f32x4 acc[4][4];
#pragma unroll
  for (int i = 0; i < 4; ++i)
#pragma unroll
    for (int j = 0; j < 4; ++j) acc[i][j] = (f32x4)(0.f);

  int la = lane & 15;
  int sl = (((lane >> 4) ^ ((la >> 1) & 3))) * 8;  // swizzled k-slot for reads

  // prologue: two stages in flight; wait only for the oldest
  STAGE(0, 0);
  STAGE(1, 1);
  asm volatile("s_waitcnt vmcnt(4)" ::: "memory");
  __builtin_amdgcn_s_barrier();
  asm volatile("" ::: "memory");

  int rd = 0, st = 2;
  for (int ks = 0; ks < 72; ++ks) {
    if (ks < 70) STAGE(ks + 2, st);  // newest stage: stays in flight across barrier
    const unsigned short* aL = As + rd * 4096;
    const unsigned short* bL = Bs + rd * 4096;
    bf16x8 af[4], bf[4];
#pragma unroll
    for (int mi = 0; mi < 4; ++mi)
      af[mi] = *(const bf16x8*)(aL + (wr * 64 + mi * 16 + la) * 32 + sl);
#pragma unroll
    for (int ni = 0; ni < 4; ++ni)
      bf[ni] = *(const bf16x8*)(bL + (wc * 64 + ni * 16 + la) * 32 + sl);
#pragma unroll
    for (int mi = 0; mi < 4; ++mi)
#pragma unroll
      for (int ni = 0; ni < 4; ++ni)
        acc[mi][ni] = __builtin_amdgcn_mfma_f32_16x16x32_bf16(af[mi], bf[ni], acc[mi][ni], 0, 0, 0);
    // wait for the (ks+1) stage only; the (ks+2) stage's 4 loads remain outstanding
    if (ks < 70) asm volatile("s_waitcnt vmcnt(4)" ::: "memory");
    else         asm volatile("s_waitcnt vmcnt(0)" ::: "memory");
    __builtin_amdgcn_s_barrier();
    asm volatile("" ::: "memory");
    rd = (rd == 2) ? 0 : rd + 1;
    st = (st == 2) ? 0 : st + 1;
  }
#undef STAGE

  int rq = lane >> 4;
#pragma unroll
  for (int mi = 0; mi < 4; ++mi) {
#pragma unroll
    for (int ni = 0; ni < 4; ++ni) {
      int colg = nt * 128 + wc * 64 + ni * 16 + la;
#pragma unroll
      for (int j = 0; j < 4; ++j) {
        int rowg = mt * 128 + wr * 64 + mi * 16 + rq * 4 + j;
        float v = acc[mi][ni][j];
        if (!isq)
          v = (v + bias[colg]) * mask[(size_t)rowg * 128 + (unsigned)colg / 3u];
        outp[(size_t)rowg * 384 + colg] = v;
      }
    }
  }
}

// 4 b per block, one wave per b: logits + where(==0) + softmax. Zero LDS/barriers.
__global__ __launch_bounds__(256) void attn_kernel4(const float* __restrict__ query,
                                                    const float* __restrict__ km,
                                                    float* __restrict__ logits,
                                                    float* __restrict__ wts) {
  int w = threadIdx.x >> 6, lane = threadIdx.x & 63;
  int b = blockIdx.x * 4 + w;
  float q[6];
#pragma unroll
  for (int j = 0; j < 6; ++j) q[j] = query[(size_t)b * 384 + lane + 64 * j];
  float lg[8];
#pragma unroll
  for (int n = 0; n < 8; ++n) {
    const float* kr = km + ((size_t)b * 8 + n) * 384;
    float p = 0.f;
#pragma unroll
    for (int j = 0; j < 6; ++j) p = fmaf(q[j], kr[lane + 64 * j], p);
    p = wave_sum(p);
    float l = p * 0.08838834764831845f;  // 1/sqrt(128)
    lg[n] = (l == 0.0f) ? -1e9f : l;
  }
  float m = lg[0];
#pragma unroll
  for (int i = 1; i < 8; ++i) m = fmaxf(m, lg[i]);
  float ex[8], s = 0.f;
#pragma unroll
  for (int i = 0; i < 8; ++i) { ex[i] = expf(lg[i] - m); s += ex[i]; }
  float inv = 1.0f / s;
  if (lane < 8) {
    float lv = lg[0], ev = ex[0];
#pragma unroll
    for (int i = 1; i < 8; ++i)
      if (lane == i) { lv = lg[i]; ev = ex[i]; }
    logits[(size_t)b * 8 + lane] = lv;
    wts[(size_t)b * 8 + lane] = ev * inv;
  }
}

// Values GEMM + fused attend + q1. One block = one b (rows (b,n,a), all 8n x 16a).
// ABF=1: A from Abf's sf-section via global_load_lds + XOR swizzle; B from WvT bf16.
// ABF=0: A from sf f32 (inline cvt), B transposed in-block from Wv f32 (fallback).
template <int ABF>
__global__ __launch_bounds__(256) void v_gemm_attend(const float* __restrict__ sf,
                                                     const unsigned short* __restrict__ Abf,
                                                     const float* __restrict__ Wv,
                                                     const unsigned short* __restrict__ WvT,
                                                     const float* __restrict__ bv,
                                                     const float* __restrict__ wts,
                                                     const float* __restrict__ task,
                                                     float* __restrict__ vm,
                                                     float* __restrict__ att,
                                                     float* __restrict__ q1) {
  __shared__ unsigned short As[2 * 4096];   // ABF=1: [2][128][32]; ABF=0: [128][40] in low part
  __shared__ unsigned short Bs[128 * 136];
  float* attL = (float*)As;                 // 16*132*4 = 8448B, used after last barrier
  int bid = blockIdx.x;
  int swz = (bid & 7) * 2048 + (bid >> 3);
  int b = swz;
  size_t m0 = (size_t)swz * 128;
  int tid = threadIdx.x;
  int wave = tid >> 6, lane = tid & 63;
  int wr = wave >> 1, wc = wave & 1;
  int r = tid >> 1, h = tid & 1;
  int la = lane & 15, lkq = lane >> 4;
  int sl = ((lkq ^ ((la >> 1) & 3))) * 8;   // swizzled A k-slot (ABF=1)

  if (ABF) {
#pragma unroll
    for (int q = 0; q < 8; ++q) {
      bf16x8 v = *(const bf16x8*)(WvT + (size_t)r * 128 + h * 64 + q * 8);
      *(bf16x8*)(Bs + r * 136 + h * 64 + q * 8) = v;
    }
  } else {
#pragma unroll
    for (int q = 0; q < 16; ++q) {
      int flat = q * 256 + tid;
      int k = flat >> 5;
      int n4 = (flat & 31) * 4;
      float4 v = *(const float4*)(Wv + (size_t)k * 128 + n4);
      Bs[(n4 + 0) * 136 + k] = f2bf(v.x);
      Bs[(n4 + 1) * 136 + k] = f2bf(v.y);
      Bs[(n4 + 2) * 136 + k] = f2bf(v.z);
      Bs[(n4 + 3) * 136 + k] = f2bf(v.w);
    }
  }

  const unsigned short *ap0 = nullptr, *ap1 = nullptr;
  int ldsA0 = wave * 1024, ldsA1 = ldsA0 + 512;
  if (ABF) {
    int p0 = wave * 128 + lane;
    int tr0 = p0 >> 2, ds0 = (p0 & 3) ^ ((tr0 >> 1) & 3);
    int p1 = p0 + 64;
    int tr1 = p1 >> 2, ds1 = (p1 & 3) ^ ((tr1 >> 1) & 3);
    ap0 = Abf + ((size_t)b * 8 + (tr0 >> 4)) * 2304 + 128 + (tr0 & 15) * 128 + ds0 * 8;
    ap1 = Abf + ((size_t)b * 8 + (tr1 >> 4)) * 2304 + 128 + (tr1 & 15) * 128 + ds1 * 8;
    __builtin_amdgcn_global_load_lds(
        (const __attribute__((address_space(1))) void*)(ap0),
        (__attribute__((address_space(3))) void*)(As + ldsA0), 16, 0, 0);
    __builtin_amdgcn_global_load_lds(
        (const __attribute__((address_space(1))) void*)(ap1),
        (__attribute__((address_space(3))) void*)(As + ldsA1), 16, 0, 0);
  }

  f32x4 acc[4][4];
#pragma unroll
  for (int i = 0; i < 4; ++i)
#pragma unroll
    for (int j = 0; j < 4; ++j) acc[i][j] = (f32x4)(0.f);

  if (ABF) __syncthreads();  // covers B ds_writes + A gload(0)

  int cur = 0;
  for (int ks = 0; ks < 4; ++ks) {
    int k0 = ks * 32;
    if (ABF) {
      if (ks < 3) {
        __builtin_amdgcn_global_load_lds(
            (const __attribute__((address_space(1))) void*)(ap0 + k0 + 32),
            (__attribute__((address_space(3))) void*)(As + (cur ^ 1) * 4096 + ldsA0), 16, 0, 0);
        __builtin_amdgcn_global_load_lds(
            (const __attribute__((address_space(1))) void*)(ap1 + k0 + 32),
            (__attribute__((address_space(3))) void*)(As + (cur ^ 1) * 4096 + ldsA1), 16, 0, 0);
      }
    } else {
      const float* ap = sf + (m0 + r) * 128 + k0 + h * 16;
      float4 v0 = *(const float4*)(ap);
      float4 v1 = *(const float4*)(ap + 4);
      float4 v2 = *(const float4*)(ap + 8);
      float4 v3 = *(const float4*)(ap + 12);
      ushort4 p0 = make_ushort4(f2bf(v0.x), f2bf(v0.y), f2bf(v0.z), f2bf(v0.w));
      ushort4 p1 = make_ushort4(f2bf(v1.x), f2bf(v1.y), f2bf(v1.z), f2bf(v1.w));
      ushort4 p2 = make_ushort4(f2bf(v2.x), f2bf(v2.y), f2bf(v2.z), f2bf(v2.w));
      ushort4 p3 = make_ushort4(f2bf(v3.x), f2bf(v3.y), f2bf(v3.z), f2bf(v3.w));
      *(ushort4*)(As + r * 40 + h * 16)      = p0;
      *(ushort4*)(As + r * 40 + h * 16 + 4)  = p1;
      *(ushort4*)(As + r * 40 + h * 16 + 8)  = p2;
      *(ushort4*)(As + r * 40 + h * 16 + 12) = p3;
      __syncthreads();
    }
    const unsigned short* aL = ABF ? (As + cur * 4096) : As;
    bf16x8 af[4], bfr[4];
#pragma unroll
    for (int mi = 0; mi < 4; ++mi) {
      int rowl = wr * 64 + mi * 16 + la;
      af[mi] = ABF ? *(const bf16x8*)(aL + rowl * 32 + sl)
                   : *(const bf16x8*)(aL + rowl * 40 + lkq * 8);
    }
#pragma unroll
    for (int ni = 0; ni < 4; ++ni)
      bfr[ni] = *(const bf16x8*)(Bs + (wc * 64 + ni * 16 + la) * 136 + k0 + lkq * 8);
#pragma unroll
    for (int mi = 0; mi < 4; ++mi)
#pragma unroll
      for (int ni = 0; ni < 4; ++ni)
        acc[mi][ni] = __builtin_amdgcn_mfma_f32_16x16x32_bf16(af[mi], bfr[ni], acc[mi][ni], 0, 0, 0);
    __syncthreads();
    cur ^= 1;
  }

  // epilogue: vm write + weighted partials over mi (n = wr*4+mi)
  float w4[4];
#pragma unroll
  for (int mi = 0; mi < 4; ++mi) w4[mi] = wts[(size_t)b * 8 + wr * 4 + mi];
  float pacc[4][4];  // [ni][j]
#pragma unroll
  for (int ni = 0; ni < 4; ++ni)
#pragma unroll
    for (int j = 0; j < 4; ++j) pacc[ni][j] = 0.f;
#pragma unroll
  for (int mi = 0; mi < 4; ++mi) {
#pragma unroll
    for (int ni = 0; ni < 4; ++ni) {
      int colg = wc * 64 + ni * 16 + la;
      float bb = bv[colg];
#pragma unroll
      for (int j = 0; j < 4; ++j) {
        size_t rowg = m0 + wr * 64 + mi * 16 + lkq * 4 + j;
        float v = acc[mi][ni][j] + bb;
        vm[rowg * 128 + colg] = v;
        pacc[ni][j] = fmaf(w4[mi], v, pacc[ni][j]);
      }
    }
  }
  // cross-wave (wr) reduce into attL[a][col], a = lkq*4+j
  if (wr == 0) {
#pragma unroll
    for (int ni = 0; ni < 4; ++ni)
#pragma unroll
      for (int j = 0; j < 4; ++j)
        attL[(lkq * 4 + j) * 132 + wc * 64 + ni * 16 + la] = pacc[ni][j];
  }
  __syncthreads();
  if (wr == 1) {
#pragma unroll
    for (int ni = 0; ni < 4; ++ni)
#pragma unroll
      for (int j = 0; j < 4; ++j)
        attL[(lkq * 4 + j) * 132 + wc * 64 + ni * 16 + la] += pacc[ni][j];
  }
  __syncthreads();
  // write attended (2048 f32) + q1 (16)
#pragma unroll
  for (int i = 0; i < 2; ++i) {
    int fidx = tid + i * 256;
    int a = fidx >> 5, c = (fidx & 31) * 4;
    f32x4 vv = *(const f32x4*)(attL + a * 132 + c);
    *(f32x4*)(att + (size_t)b * 2048 + a * 128 + c) = vv;
  }
  for (int j = wave; j < 16; j += 4) {
    float p = task[(size_t)b * 1024 + lane] * attL[j * 132 + lane]
            + task[(size_t)b * 1024 + 64 + lane] * attL[j * 132 + 64 + lane];
    p = wave_sum(p);
    if (lane == 0) q1[(size_t)b * 16 + j] = p;
  }
}

extern "C" void kernel_launch(void* const* d_in, const int* in_sizes, int n_in,
                              void* d_out, int out_size, void* d_ws, size_t ws_size,
                              hipStream_t stream) {
  const float* basis = (const float*)d_in[0];
  const float* sf    = (const float*)d_in[1];
  const float* task  = (const float*)d_in[2];
  const float* mask  = (const float*)d_in[3];
  const float* Wq    = (const float*)d_in[4];
  const float* Wk    = (const float*)d_in[5];
  const float* bk    = (const float*)d_in[6];
  const float* Wv    = (const float*)d_in[7];
  const float* bv    = (const float*)d_in[8];

  float* out  = (float*)d_out;
  float* q1   = out;
  float* att  = out + OFF_ATT;
  float* logi = out + OFF_LOG;
  float* wts  = out + OFF_W;
  float* km   = out + OFF_KM;
  float* vm   = out + OFF_VM;
  float* simo = out + OFF_SIM;

  // d_ws layout (preferred path): Abf | WkT | WqT | WvT | query | invn = ~634MB.
  constexpr size_t WS_NEED = 603979776ull + 1769472ull + 1769472ull + 32768ull +
                             25165824ull + 524288ull;
  bool usews = ws_size >= WS_NEED;

  unsigned short *Abf, *WkT, *WqT, *WvT = nullptr;
  float *query, *invn;
  if (usews) {
    unsigned char* ws = (unsigned char*)d_ws;
    Abf   = (unsigned short*)ws;
    WkT   = (unsigned short*)(ws + 603979776ull);
    WqT   = (unsigned short*)(ws + 605749248ull);
    WvT   = (unsigned short*)(ws + 607518720ull);
    query = (float*)(ws + 607551488ull);
    invn  = (float*)(ws + 632717312ull);
  } else {
    // fallback stashes: Abf in vm region (consumed by qk2 before v_gemm_attend
    // overwrites vm); query/invn/WkT/WqT in att region (all consumed before
    // v_gemm_attend, the only att writer, launches).
    query = att;                                     // 6,291,456 f32
    invn  = att + 6291456;                           //   131,072 f32
    WkT   = (unsigned short*)(att + 6422528);        //   884,736 bf16
    WqT   = WkT + 884736;                            //   884,736 bf16
    Abf   = (unsigned short*)vm;                     // 301,989,888 bf16
  }

  norm_kernel<<<32768, 256, 0, stream>>>(task, invn, simo);
  wprep_t<<<216, 256, 0, stream>>>(Wk, WkT, 2304, 384);
  wprep_t<<<216, 256, 0, stream>>>(Wq, WqT, 2304, 384);
  if (usews) wprep_t<<<4, 256, 0, stream>>>(Wv, WvT, 128, 128);
  abuild_sim<<<16384, 576, 0, stream>>>(basis, sf, task, invn, Abf, simo);
  // combined keys (3072 blocks) + query (384 blocks): counted-vmcnt triple-buffer
  qk2<<<3456, 256, 0, stream>>>(Abf, WkT, WqT, bk, mask, km, query);
  attn_kernel4<<<4096, 256, 0, stream>>>(query, km, logi, wts);
  // values GEMM + fused attend/q1
  if (usews)
    v_gemm_attend<1><<<16384, 256, 0, stream>>>(sf, Abf, Wv, WvT, bv, wts, task, vm, att, q1);
  else
    v_gemm_attend<0><<<16384, 256, 0, stream>>>(sf, nullptr, Wv, nullptr, bv, wts, task, vm, att, q1);
}

// Round 11
// 1293.627 us; speedup vs baseline: 1.1668x; 1.0808x over previous
//
#include <hip/hip_runtime.h>
#include <hip/hip_bf16.h>
#include <math.h>

// B=16384, NB=8, NA=16, D=128, IN_DIM=2304, QK_DIM=384, V_DIM=128
static constexpr size_t OFF_ATT = 262144;      // attended_sf (33,554,432 f32)
static constexpr size_t OFF_LOG = 33816576;    // attn_logits
static constexpr size_t OFF_W   = 33947648;    // attention_weights
static constexpr size_t OFF_KM  = 34078720;    // keys_masked
static constexpr size_t OFF_VM  = 84410368;    // values_masked (268,435,456 f32)
static constexpr size_t OFF_SIM = 352845824;   // sim (7)

typedef short bf16x8 __attribute__((ext_vector_type(8)));
typedef float f32x4 __attribute__((ext_vector_type(4)));

__device__ inline unsigned short f2bf(float f) {
  union { float f; unsigned u; } x; x.f = f;
  unsigned r = x.u + 0x7FFFu + ((x.u >> 16) & 1u);  // RNE
  return (unsigned short)(r >> 16);
}

__device__ inline float wave_sum(float v) {
#pragma unroll
  for (int o = 32; o > 0; o >>= 1) v += __shfl_xor(v, o, 64);
  return v;
}

// One wave per (b,n) row: inverse L2 norm of task rows. Also zero sim slots.
__global__ void norm_kernel(const float* __restrict__ task, float* __restrict__ invn,
                            float* __restrict__ simo) {
  int idx = blockIdx.x * 4 + (threadIdx.x >> 6);
  int lane = threadIdx.x & 63;
  float t0 = task[(size_t)idx * 128 + lane];
  float t1 = task[(size_t)idx * 128 + 64 + lane];
  float s = wave_sum(t0 * t0 + t1 * t1);
  if (lane == 0) invn[idx] = rsqrtf(s);
  if (blockIdx.x == 0 && threadIdx.x < 7) simo[threadIdx.x] = 0.0f;
}

// Tiled transpose+cvt: WT[n][k] = bf16(W[k][n]). 64x64 tiles, coalesced both sides.
__global__ void wprep_t(const float* __restrict__ W, unsigned short* __restrict__ WT,
                        int K, int N) {
  int ntn = N >> 6;
  int kt = blockIdx.x / ntn, nt = blockIdx.x % ntn;
  int k0 = kt * 64, n0 = nt * 64;
  __shared__ float t[64][65];
  int tid = threadIdx.x;
  int r = tid >> 2, c0 = (tid & 3) * 16;
#pragma unroll
  for (int q = 0; q < 4; ++q) {
    float4 v = *(const float4*)(W + (size_t)(k0 + r) * N + n0 + c0 + q * 4);
    t[r][c0 + q * 4 + 0] = v.x; t[r][c0 + q * 4 + 1] = v.y;
    t[r][c0 + q * 4 + 2] = v.z; t[r][c0 + q * 4 + 3] = v.w;
  }
  __syncthreads();
  int n = tid >> 2, kc0 = (tid & 3) * 16;
#pragma unroll
  for (int q = 0; q < 4; ++q) {
    int kc = kc0 + q * 4;
    ushort4 o = make_ushort4(f2bf(t[kc + 0][n]), f2bf(t[kc + 1][n]),
                             f2bf(t[kc + 2][n]), f2bf(t[kc + 3][n]));
    *(ushort4*)(WT + (size_t)(n0 + n) * K + k0 + kc) = o;
  }
}

// One block (576 thr) per b: thread owns one float4-chunk f of the 2304-row.
// Loads all 8 rows' chunks (independent), writes bf16 Abf, and accumulates the
// 7 consecutive-row squared-diff partials in registers.
__global__ __launch_bounds__(576) void abuild_sim(const float* __restrict__ basis,
                                                  const float* __restrict__ sf,
                                                  const float* __restrict__ task,
                                                  const float* __restrict__ invn,
                                                  unsigned short* __restrict__ Abf,
                                                  float* __restrict__ simo) {
  int b = blockIdx.x;
  int f = threadIdx.x;  // 0..575
  size_t row0 = (size_t)b * 8;
  float4 v[8];
#pragma unroll
  for (int n = 0; n < 8; ++n) {
    size_t row = row0 + n;
    float4 x;
    if (f < 32)       x = *(const float4*)(basis + row * 128 + f * 4);
    else if (f < 544) x = *(const float4*)(sf + row * 2048 + (f - 32) * 4);
    else {
      x = *(const float4*)(task + row * 128 + (f - 544) * 4);
      float s = invn[row];
      x.x *= s; x.y *= s; x.z *= s; x.w *= s;
    }
    v[n] = x;
    ushort4 o = make_ushort4(f2bf(x.x), f2bf(x.y), f2bf(x.z), f2bf(x.w));
    *(ushort4*)(Abf + row * 2304 + f * 4) = o;
  }
  float s7[7];
#pragma unroll
  for (int n = 1; n < 8; ++n) {
    float dx = v[n].x - v[n - 1].x, dy = v[n].y - v[n - 1].y;
    float dz = v[n].z - v[n - 1].z, dw = v[n].w - v[n - 1].w;
    s7[n - 1] = dx * dx + dy * dy + dz * dz + dw * dw;
  }
  __shared__ float red[9][7];
  int wid = threadIdx.x >> 6, lane = threadIdx.x & 63;
#pragma unroll
  for (int i = 0; i < 7; ++i) {
    float p = wave_sum(s7[i]);
    if (lane == 0) red[wid][i] = p;
  }
  __syncthreads();
  if (threadIdx.x < 7) {
    float s = 0.f;
#pragma unroll
    for (int w = 0; w < 9; ++w) s += red[w][threadIdx.x];
    atomicAdd(&simo[threadIdx.x], expf(-0.5f * s) * (1.0f / 16384.0f));
  }
}

// Combined keys+query MFMA GEMM (r8's proven 2-phase double-buffer body):
// blocks [0,3072) keys (M=131072, +bias,*mask), blocks [3072,3456) query
// (M=16384, A rows stride 8). 128x128 tile, BK=32, 4 waves, 32KB LDS
// (5 blocks/CU). global_load_lds 16B staging, XOR involution swizzle.
__global__ __launch_bounds__(256) void qk2(const unsigned short* __restrict__ Abf,
                                           const unsigned short* __restrict__ WkT,
                                           const unsigned short* __restrict__ WqT,
                                           const float* __restrict__ bias,
                                           const float* __restrict__ mask,
                                           float* __restrict__ km,
                                           float* __restrict__ query) {
  __shared__ unsigned short As[2 * 4096];
  __shared__ unsigned short Bs[2 * 4096];
  int bid = blockIdx.x;
  bool isq = bid >= 3072;
  int mt, nt;
  const unsigned short* WT;
  float* outp;
  if (!isq) {
    int swz = (bid & 7) * 384 + (bid >> 3);
    mt = swz / 3; nt = swz - mt * 3;
    WT = WkT; outp = km;
  } else {
    int q = bid - 3072;
    int swz = (q & 7) * 48 + (q >> 3);
    mt = swz / 3; nt = swz - mt * 3;
    WT = WqT; outp = query;
  }
  int tid = threadIdx.x;
  int wave = tid >> 6, lane = tid & 63;
  int wr = wave >> 1, wc = wave & 1;
  int m0g = mt * 128, n0g = nt * 128;

  // staging: physical chunk p = wave*128 + lane (+64); row = p>>2;
  // global k-slot pre-swizzled by the involution slot^((row>>1)&3)
  int c_lo = wave * 128 + lane;
  int row_q0 = c_lo >> 2, kc_q0 = ((c_lo & 3) ^ ((row_q0 >> 1) & 3)) * 8;
  int c_hi = c_lo + 64;
  int row_q1 = c_hi >> 2, kc_q1 = ((c_hi & 3) ^ ((row_q1 >> 1) & 3)) * 8;
  size_t ga_q0 = isq ? (size_t)(m0g + row_q0) * 8 : (size_t)(m0g + row_q0);
  size_t ga_q1 = isq ? (size_t)(m0g + row_q1) * 8 : (size_t)(m0g + row_q1);
  const unsigned short* ag0 = Abf + ga_q0 * 2304 + kc_q0;
  const unsigned short* ag1 = Abf + ga_q1 * 2304 + kc_q1;
  const unsigned short* bg0 = WT + (size_t)(n0g + row_q0) * 2304 + kc_q0;
  const unsigned short* bg1 = WT + (size_t)(n0g + row_q1) * 2304 + kc_q1;
  int ldsoff0 = wave * 1024;  // elements; wave-uniform (HW adds lane*16B)
  int ldsoff1 = ldsoff0 + 512;

#define STAGE(ks, cur)                                                                   \
  do {                                                                                   \
    int _k0 = (ks) * 32;                                                                 \
    unsigned short* _a = As + (cur) * 4096;                                              \
    unsigned short* _b = Bs + (cur) * 4096;                                              \
    __builtin_amdgcn_global_load_lds(                                                    \
        (const __attribute__((address_space(1))) void*)(ag0 + _k0),                      \
        (__attribute__((address_space(3))) void*)(_a + ldsoff0), 16, 0, 0);              \
    __builtin_amdgcn_global_load_lds(                                                    \
        (const __attribute__((address_space(1))) void*)(ag1 + _k0),                      \
        (__attribute__((address_space(3))) void*)(_a + ldsoff1), 16, 0, 0);              \
    __builtin_amdgcn_global_load_lds(                                                    \
        (const __attribute__((address_space(1))) void*)(bg0 + _k0),                      \
        (__attribute__((address_space(3))) void*)(_b + ldsoff0), 16, 0, 0);              \
    __builtin_amdgcn_global_load_lds(                                                    \
        (const __attribute__((address_space(1))) void*)(bg1 + _k0),                      \
        (__attribute__((address_space(3))) void*)(_b + ldsoff1), 16, 0, 0);              \
  } while (0)

  f32x4 acc[4][4];
#pragma unroll
  for (int i = 0; i < 4; ++i)
#pragma unroll
    for (int j = 0; j < 4; ++j) acc[i][j] = (f32x4)(0.f);

  int la = lane & 15;
  int sl = (((lane >> 4) ^ ((la >> 1) & 3))) * 8;  // swizzled k-slot for reads

  STAGE(0, 0);
  __syncthreads();
  int cur = 0;
  for (int ks = 0; ks < 72; ++ks) {
    if (ks < 71) STAGE(ks + 1, cur ^ 1);   // prefetch overlaps ds_read+MFMA below
    const unsigned short* aL = As + cur * 4096;
    const unsigned short* bL = Bs + cur * 4096;
    bf16x8 af[4], bf[4];
#pragma unroll
    for (int mi = 0; mi < 4; ++mi)
      af[mi] = *(const bf16x8*)(aL + (wr * 64 + mi * 16 + la) * 32 + sl);
#pragma unroll
    for (int ni = 0; ni < 4; ++ni)
      bf[ni] = *(const bf16x8*)(bL + (wc * 64 + ni * 16 + la) * 32 + sl);
#pragma unroll
    for (int mi = 0; mi < 4; ++mi)
#pragma unroll
      for (int ni = 0; ni < 4; ++ni)
        acc[mi][ni] = __builtin_amdgcn_mfma_f32_16x16x32_bf16(af[mi], bf[ni], acc[mi][ni], 0, 0, 0);
    __syncthreads();
    cur ^= 1;
  }
#undef STAGE

  int rq = lane >> 4;
#pragma unroll
  for (int mi = 0; mi < 4; ++mi) {
#pragma unroll
    for (int ni = 0; ni < 4; ++ni) {
      int colg = nt * 128 + wc * 64 + ni * 16 + la;
#pragma unroll
      for (int j = 0; j < 4; ++j) {
        int rowg = mt * 128 + wr * 64 + mi * 16 + rq * 4 + j;
        float v = acc[mi][ni][j];
        if (!isq)
          v = (v + bias[colg]) * mask[(size_t)rowg * 128 + (unsigned)colg / 3u];
        outp[(size_t)rowg * 384 + colg] = v;
      }
    }
  }
}

// 4 b per block, one wave per b: logits + where(==0) + softmax. Zero LDS/barriers.
__global__ __launch_bounds__(256) void attn_kernel4(const float* __restrict__ query,
                                                    const float* __restrict__ km,
                                                    float* __restrict__ logits,
                                                    float* __restrict__ wts) {
  int w = threadIdx.x >> 6, lane = threadIdx.x & 63;
  int b = blockIdx.x * 4 + w;
  float q[6];
#pragma unroll
  for (int j = 0; j < 6; ++j) q[j] = query[(size_t)b * 384 + lane + 64 * j];
  float lg[8];
#pragma unroll
  for (int n = 0; n < 8; ++n) {
    const float* kr = km + ((size_t)b * 8 + n) * 384;
    float p = 0.f;
#pragma unroll
    for (int j = 0; j < 6; ++j) p = fmaf(q[j], kr[lane + 64 * j], p);
    p = wave_sum(p);
    float l = p * 0.08838834764831845f;  // 1/sqrt(128)
    lg[n] = (l == 0.0f) ? -1e9f : l;
  }
  float m = lg[0];
#pragma unroll
  for (int i = 1; i < 8; ++i) m = fmaxf(m, lg[i]);
  float ex[8], s = 0.f;
#pragma unroll
  for (int i = 0; i < 8; ++i) { ex[i] = expf(lg[i] - m); s += ex[i]; }
  float inv = 1.0f / s;
  if (lane < 8) {
    float lv = lg[0], ev = ex[0];
#pragma unroll
    for (int i = 1; i < 8; ++i)
      if (lane == i) { lv = lg[i]; ev = ex[i]; }
    logits[(size_t)b * 8 + lane] = lv;
    wts[(size_t)b * 8 + lane] = ev * inv;
  }
}

// Values GEMM + fused attend + q1. One block = one b (rows (b,n,a), all 8n x 16a).
// ABF=1: A from Abf's sf-section via global_load_lds + XOR swizzle; B from WvT bf16.
// ABF=0: A from sf f32 (inline cvt), B transposed in-block from Wv f32 (fallback).
template <int ABF>
__global__ __launch_bounds__(256) void v_gemm_attend(const float* __restrict__ sf,
                                                     const unsigned short* __restrict__ Abf,
                                                     const float* __restrict__ Wv,
                                                     const unsigned short* __restrict__ WvT,
                                                     const float* __restrict__ bv,
                                                     const float* __restrict__ wts,
                                                     const float* __restrict__ task,
                                                     float* __restrict__ vm,
                                                     float* __restrict__ att,
                                                     float* __restrict__ q1) {
  __shared__ unsigned short As[2 * 4096];   // ABF=1: [2][128][32]; ABF=0: [128][40] in low part
  __shared__ unsigned short Bs[128 * 136];
  float* attL = (float*)As;                 // 16*132*4 = 8448B, used after last barrier
  int bid = blockIdx.x;
  int swz = (bid & 7) * 2048 + (bid >> 3);
  int b = swz;
  size_t m0 = (size_t)swz * 128;
  int tid = threadIdx.x;
  int wave = tid >> 6, lane = tid & 63;
  int wr = wave >> 1, wc = wave & 1;
  int r = tid >> 1, h = tid & 1;
  int la = lane & 15, lkq = lane >> 4;
  int sl = ((lkq ^ ((la >> 1) & 3))) * 8;   // swizzled A k-slot (ABF=1)

  if (ABF) {
#pragma unroll
    for (int q = 0; q < 8; ++q) {
      bf16x8 v = *(const bf16x8*)(WvT + (size_t)r * 128 + h * 64 + q * 8);
      *(bf16x8*)(Bs + r * 136 + h * 64 + q * 8) = v;
    }
  } else {
#pragma unroll
    for (int q = 0; q < 16; ++q) {
      int flat = q * 256 + tid;
      int k = flat >> 5;
      int n4 = (flat & 31) * 4;
      float4 v = *(const float4*)(Wv + (size_t)k * 128 + n4);
      Bs[(n4 + 0) * 136 + k] = f2bf(v.x);
      Bs[(n4 + 1) * 136 + k] = f2bf(v.y);
      Bs[(n4 + 2) * 136 + k] = f2bf(v.z);
      Bs[(n4 + 3) * 136 + k] = f2bf(v.w);
    }
  }

  const unsigned short *ap0 = nullptr, *ap1 = nullptr;
  int ldsA0 = wave * 1024, ldsA1 = ldsA0 + 512;
  if (ABF) {
    int p0 = wave * 128 + lane;
    int tr0 = p0 >> 2, ds0 = (p0 & 3) ^ ((tr0 >> 1) & 3);
    int p1 = p0 + 64;
    int tr1 = p1 >> 2, ds1 = (p1 & 3) ^ ((tr1 >> 1) & 3);
    ap0 = Abf + ((size_t)b * 8 + (tr0 >> 4)) * 2304 + 128 + (tr0 & 15) * 128 + ds0 * 8;
    ap1 = Abf + ((size_t)b * 8 + (tr1 >> 4)) * 2304 + 128 + (tr1 & 15) * 128 + ds1 * 8;
    __builtin_amdgcn_global_load_lds(
        (const __attribute__((address_space(1))) void*)(ap0),
        (__attribute__((address_space(3))) void*)(As + ldsA0), 16, 0, 0);
    __builtin_amdgcn_global_load_lds(
        (const __attribute__((address_space(1))) void*)(ap1),
        (__attribute__((address_space(3))) void*)(As + ldsA1), 16, 0, 0);
  }

  f32x4 acc[4][4];
#pragma unroll
  for (int i = 0; i < 4; ++i)
#pragma unroll
    for (int j = 0; j < 4; ++j) acc[i][j] = (f32x4)(0.f);

  if (ABF) __syncthreads();  // covers B ds_writes + A gload(0)

  int cur = 0;
  for (int ks = 0; ks < 4; ++ks) {
    int k0 = ks * 32;
    if (ABF) {
      if (ks < 3) {
        __builtin_amdgcn_global_load_lds(
            (const __attribute__((address_space(1))) void*)(ap0 + k0 + 32),
            (__attribute__((address_space(3))) void*)(As + (cur ^ 1) * 4096 + ldsA0), 16, 0, 0);
        __builtin_amdgcn_global_load_lds(
            (const __attribute__((address_space(1))) void*)(ap1 + k0 + 32),
            (__attribute__((address_space(3))) void*)(As + (cur ^ 1) * 4096 + ldsA1), 16, 0, 0);
      }
    } else {
      const float* ap = sf + (m0 + r) * 128 + k0 + h * 16;
      float4 v0 = *(const float4*)(ap);
      float4 v1 = *(const float4*)(ap + 4);
      float4 v2 = *(const float4*)(ap + 8);
      float4 v3 = *(const float4*)(ap + 12);
      ushort4 p0 = make_ushort4(f2bf(v0.x), f2bf(v0.y), f2bf(v0.z), f2bf(v0.w));
      ushort4 p1 = make_ushort4(f2bf(v1.x), f2bf(v1.y), f2bf(v1.z), f2bf(v1.w));
      ushort4 p2 = make_ushort4(f2bf(v2.x), f2bf(v2.y), f2bf(v2.z), f2bf(v2.w));
      ushort4 p3 = make_ushort4(f2bf(v3.x), f2bf(v3.y), f2bf(v3.z), f2bf(v3.w));
      *(ushort4*)(As + r * 40 + h * 16)      = p0;
      *(ushort4*)(As + r * 40 + h * 16 + 4)  = p1;
      *(ushort4*)(As + r * 40 + h * 16 + 8)  = p2;
      *(ushort4*)(As + r * 40 + h * 16 + 12) = p3;
      __syncthreads();
    }
    const unsigned short* aL = ABF ? (As + cur * 4096) : As;
    bf16x8 af[4], bfr[4];
#pragma unroll
    for (int mi = 0; mi < 4; ++mi) {
      int rowl = wr * 64 + mi * 16 + la;
      af[mi] = ABF ? *(const bf16x8*)(aL + rowl * 32 + sl)
                   : *(const bf16x8*)(aL + rowl * 40 + lkq * 8);
    }
#pragma unroll
    for (int ni = 0; ni < 4; ++ni)
      bfr[ni] = *(const bf16x8*)(Bs + (wc * 64 + ni * 16 + la) * 136 + k0 + lkq * 8);
#pragma unroll
    for (int mi = 0; mi < 4; ++mi)
#pragma unroll
      for (int ni = 0; ni < 4; ++ni)
        acc[mi][ni] = __builtin_amdgcn_mfma_f32_16x16x32_bf16(af[mi], bfr[ni], acc[mi][ni], 0, 0, 0);
    __syncthreads();
    cur ^= 1;
  }

  // epilogue: vm write + weighted partials over mi (n = wr*4+mi)
  float w4[4];
#pragma unroll
  for (int mi = 0; mi < 4; ++mi) w4[mi] = wts[(size_t)b * 8 + wr * 4 + mi];
  float pacc[4][4];  // [ni][j]
#pragma unroll
  for (int ni = 0; ni < 4; ++ni)
#pragma unroll
    for (int j = 0; j < 4; ++j) pacc[ni][j] = 0.f;
#pragma unroll
  for (int mi = 0; mi < 4; ++mi) {
#pragma unroll
    for (int ni = 0; ni < 4; ++ni) {
      int colg = wc * 64 + ni * 16 + la;
      float bb = bv[colg];
#pragma unroll
      for (int j = 0; j < 4; ++j) {
        size_t rowg = m0 + wr * 64 + mi * 16 + lkq * 4 + j;
        float v = acc[mi][ni][j] + bb;
        vm[rowg * 128 + colg] = v;
        pacc[ni][j] = fmaf(w4[mi], v, pacc[ni][j]);
      }
    }
  }
  // cross-wave (wr) reduce into attL[a][col], a = lkq*4+j
  if (wr == 0) {
#pragma unroll
    for (int ni = 0; ni < 4; ++ni)
#pragma unroll
      for (int j = 0; j < 4; ++j)
        attL[(lkq * 4 + j) * 132 + wc * 64 + ni * 16 + la] = pacc[ni][j];
  }
  __syncthreads();
  if (wr == 1) {
#pragma unroll
    for (int ni = 0; ni < 4; ++ni)
#pragma unroll
      for (int j = 0; j < 4; ++j)
        attL[(lkq * 4 + j) * 132 + wc * 64 + ni * 16 + la] += pacc[ni][j];
  }
  __syncthreads();
  // write attended (2048 f32) + q1 (16)
#pragma unroll
  for (int i = 0; i < 2; ++i) {
    int fidx = tid + i * 256;
    int a = fidx >> 5, c = (fidx & 31) * 4;
    f32x4 vv = *(const f32x4*)(attL + a * 132 + c);
    *(f32x4*)(att + (size_t)b * 2048 + a * 128 + c) = vv;
  }
  for (int j = wave; j < 16; j += 4) {
    float p = task[(size_t)b * 1024 + lane] * attL[j * 132 + lane]
            + task[(size_t)b * 1024 + 64 + lane] * attL[j * 132 + 64 + lane];
    p = wave_sum(p);
    if (lane == 0) q1[(size_t)b * 16 + j] = p;
  }
}

extern "C" void kernel_launch(void* const* d_in, const int* in_sizes, int n_in,
                              void* d_out, int out_size, void* d_ws, size_t ws_size,
                              hipStream_t stream) {
  const float* basis = (const float*)d_in[0];
  const float* sf    = (const float*)d_in[1];
  const float* task  = (const float*)d_in[2];
  const float* mask  = (const float*)d_in[3];
  const float* Wq    = (const float*)d_in[4];
  const float* Wk    = (const float*)d_in[5];
  const float* bk    = (const float*)d_in[6];
  const float* Wv    = (const float*)d_in[7];
  const float* bv    = (const float*)d_in[8];

  float* out  = (float*)d_out;
  float* q1   = out;
  float* att  = out + OFF_ATT;
  float* logi = out + OFF_LOG;
  float* wts  = out + OFF_W;
  float* km   = out + OFF_KM;
  float* vm   = out + OFF_VM;
  float* simo = out + OFF_SIM;

  // d_ws layout (preferred path): Abf | WkT | WqT | WvT | query | invn = ~634MB.
  constexpr size_t WS_NEED = 603979776ull + 1769472ull + 1769472ull + 32768ull +
                             25165824ull + 524288ull;
  bool usews = ws_size >= WS_NEED;

  unsigned short *Abf, *WkT, *WqT, *WvT = nullptr;
  float *query, *invn;
  if (usews) {
    unsigned char* ws = (unsigned char*)d_ws;
    Abf   = (unsigned short*)ws;
    WkT   = (unsigned short*)(ws + 603979776ull);
    WqT   = (unsigned short*)(ws + 605749248ull);
    WvT   = (unsigned short*)(ws + 607518720ull);
    query = (float*)(ws + 607551488ull);
    invn  = (float*)(ws + 632717312ull);
  } else {
    // fallback stashes: Abf in vm region (consumed by qk2 before v_gemm_attend
    // overwrites vm); query/invn/WkT/WqT in att region (all consumed before
    // v_gemm_attend, the only att writer, launches).
    query = att;                                     // 6,291,456 f32
    invn  = att + 6291456;                           //   131,072 f32
    WkT   = (unsigned short*)(att + 6422528);        //   884,736 bf16
    WqT   = WkT + 884736;                            //   884,736 bf16
    Abf   = (unsigned short*)vm;                     // 301,989,888 bf16
  }

  norm_kernel<<<32768, 256, 0, stream>>>(task, invn, simo);
  wprep_t<<<216, 256, 0, stream>>>(Wk, WkT, 2304, 384);
  wprep_t<<<216, 256, 0, stream>>>(Wq, WqT, 2304, 384);
  if (usews) wprep_t<<<4, 256, 0, stream>>>(Wv, WvT, 128, 128);
  abuild_sim<<<16384, 576, 0, stream>>>(basis, sf, task, invn, Abf, simo);
  // combined keys (3072 blocks) + query (384 blocks), r8 2-phase body
  qk2<<<3456, 256, 0, stream>>>(Abf, WkT, WqT, bk, mask, km, query);
  attn_kernel4<<<4096, 256, 0, stream>>>(query, km, logi, wts);
  // values GEMM + fused attend/q1
  if (usews)
    v_gemm_attend<1><<<16384, 256, 0, stream>>>(sf, Abf, Wv, WvT, bv, wts, task, vm, att, q1);
  else
    v_gemm_attend<0><<<16384, 256, 0, stream>>>(sf, nullptr, Wv, nullptr, bv, wts, task, vm, att, q1);
}

// Round 12
// 1255.294 us; speedup vs baseline: 1.2025x; 1.0305x over previous
//
#include <hip/hip_runtime.h>
#include <hip/hip_bf16.h>
#include <math.h>

// B=16384, NB=8, NA=16, D=128, IN_DIM=2304, QK_DIM=384, V_DIM=128
static constexpr size_t OFF_ATT = 262144;      // attended_sf (33,554,432 f32)
static constexpr size_t OFF_LOG = 33816576;    // attn_logits
static constexpr size_t OFF_W   = 33947648;    // attention_weights
static constexpr size_t OFF_KM  = 34078720;    // keys_masked
static constexpr size_t OFF_VM  = 84410368;    // values_masked (268,435,456 f32)
static constexpr size_t OFF_SIM = 352845824;   // sim (7)

typedef short bf16x8 __attribute__((ext_vector_type(8)));
typedef float f32x4 __attribute__((ext_vector_type(4)));

__device__ inline unsigned short f2bf(float f) {
  union { float f; unsigned u; } x; x.f = f;
  unsigned r = x.u + 0x7FFFu + ((x.u >> 16) & 1u);  // RNE
  return (unsigned short)(r >> 16);
}

__device__ inline float wave_sum(float v) {
#pragma unroll
  for (int o = 32; o > 0; o >>= 1) v += __shfl_xor(v, o, 64);
  return v;
}

// FALLBACK only: one wave per (b,n) row inverse L2 norm + zero sim slots.
__global__ void norm_kernel(const float* __restrict__ task, float* __restrict__ invn,
                            float* __restrict__ simo) {
  int idx = blockIdx.x * 4 + (threadIdx.x >> 6);
  int lane = threadIdx.x & 63;
  float t0 = task[(size_t)idx * 128 + lane];
  float t1 = task[(size_t)idx * 128 + 64 + lane];
  float s = wave_sum(t0 * t0 + t1 * t1);
  if (lane == 0) invn[idx] = rsqrtf(s);
  if (blockIdx.x == 0 && threadIdx.x < 7) simo[threadIdx.x] = 0.0f;
}

// Tiled transpose+cvt for all three weights in one dispatch (436 blocks):
// [0,216) Wk, [216,432) Wq, [432,436) Wv. WT[n][k] = bf16(W[k][n]).
__global__ void wprep3(const float* __restrict__ Wk, const float* __restrict__ Wq,
                       const float* __restrict__ Wv,
                       unsigned short* __restrict__ WkT, unsigned short* __restrict__ WqT,
                       unsigned short* __restrict__ WvT) {
  int bb = blockIdx.x;
  const float* W; unsigned short* WT; int K, N, b2;
  if (bb < 216)      { W = Wk; WT = WkT; K = 2304; N = 384; b2 = bb; }
  else if (bb < 432) { W = Wq; WT = WqT; K = 2304; N = 384; b2 = bb - 216; }
  else               { W = Wv; WT = WvT; K = 128;  N = 128; b2 = bb - 432; }
  int ntn = N >> 6;
  int kt = b2 / ntn, nt = b2 % ntn;
  int k0 = kt * 64, n0 = nt * 64;
  __shared__ float t[64][65];
  int tid = threadIdx.x;
  int r = tid >> 2, c0 = (tid & 3) * 16;
#pragma unroll
  for (int q = 0; q < 4; ++q) {
    float4 v = *(const float4*)(W + (size_t)(k0 + r) * N + n0 + c0 + q * 4);
    t[r][c0 + q * 4 + 0] = v.x; t[r][c0 + q * 4 + 1] = v.y;
    t[r][c0 + q * 4 + 2] = v.z; t[r][c0 + q * 4 + 3] = v.w;
  }
  __syncthreads();
  int n = tid >> 2, kc0 = (tid & 3) * 16;
#pragma unroll
  for (int q = 0; q < 4; ++q) {
    int kc = kc0 + q * 4;
    ushort4 o = make_ushort4(f2bf(t[kc + 0][n]), f2bf(t[kc + 1][n]),
                             f2bf(t[kc + 2][n]), f2bf(t[kc + 3][n]));
    *(ushort4*)(WT + (size_t)(n0 + n) * K + k0 + kc) = o;
  }
}

// Legacy wprep (fallback path, per-weight).
__global__ void wprep_t(const float* __restrict__ W, unsigned short* __restrict__ WT,
                        int K, int N) {
  int ntn = N >> 6;
  int kt = blockIdx.x / ntn, nt = blockIdx.x % ntn;
  int k0 = kt * 64, n0 = nt * 64;
  __shared__ float t[64][65];
  int tid = threadIdx.x;
  int r = tid >> 2, c0 = (tid & 3) * 16;
#pragma unroll
  for (int q = 0; q < 4; ++q) {
    float4 v = *(const float4*)(W + (size_t)(k0 + r) * N + n0 + c0 + q * 4);
    t[r][c0 + q * 4 + 0] = v.x; t[r][c0 + q * 4 + 1] = v.y;
    t[r][c0 + q * 4 + 2] = v.z; t[r][c0 + q * 4 + 3] = v.w;
  }
  __syncthreads();
  int n = tid >> 2, kc0 = (tid & 3) * 16;
#pragma unroll
  for (int q = 0; q < 4; ++q) {
    int kc = kc0 + q * 4;
    ushort4 o = make_ushort4(f2bf(t[kc + 0][n]), f2bf(t[kc + 1][n]),
                             f2bf(t[kc + 2][n]), f2bf(t[kc + 3][n]));
    *(ushort4*)(WT + (size_t)(n0 + n) * K + k0 + kc) = o;
  }
}

// One block (576 thr) per b with FUSED task-norm: task-section threads
// (lanes 32..63 of wave 8) butterfly-reduce the row sumsq in-register.
__global__ __launch_bounds__(576) void abuild_sim_fn(const float* __restrict__ basis,
                                                     const float* __restrict__ sf,
                                                     const float* __restrict__ task,
                                                     unsigned short* __restrict__ Abf,
                                                     float* __restrict__ simo) {
  int b = blockIdx.x;
  int f = threadIdx.x;  // 0..575
  size_t row0 = (size_t)b * 8;
  float4 v[8];
  if (f >= 544) {
    float ss[8];
#pragma unroll
    for (int n = 0; n < 8; ++n) {
      float4 x = *(const float4*)(task + (row0 + n) * 128 + (f - 544) * 4);
      v[n] = x;
      ss[n] = x.x * x.x + x.y * x.y + x.z * x.z + x.w * x.w;
    }
#pragma unroll
    for (int n = 0; n < 8; ++n) {
#pragma unroll
      for (int o = 16; o > 0; o >>= 1) ss[n] += __shfl_xor(ss[n], o, 64);
      float iv = rsqrtf(ss[n]);
      v[n].x *= iv; v[n].y *= iv; v[n].z *= iv; v[n].w *= iv;
    }
  } else if (f < 32) {
#pragma unroll
    for (int n = 0; n < 8; ++n) v[n] = *(const float4*)(basis + (row0 + n) * 128 + f * 4);
  } else {
#pragma unroll
    for (int n = 0; n < 8; ++n) v[n] = *(const float4*)(sf + (row0 + n) * 2048 + (f - 32) * 4);
  }
#pragma unroll
  for (int n = 0; n < 8; ++n) {
    ushort4 o = make_ushort4(f2bf(v[n].x), f2bf(v[n].y), f2bf(v[n].z), f2bf(v[n].w));
    *(ushort4*)(Abf + (row0 + n) * 2304 + f * 4) = o;
  }
  float s7[7];
#pragma unroll
  for (int n = 1; n < 8; ++n) {
    float dx = v[n].x - v[n - 1].x, dy = v[n].y - v[n - 1].y;
    float dz = v[n].z - v[n - 1].z, dw = v[n].w - v[n - 1].w;
    s7[n - 1] = dx * dx + dy * dy + dz * dz + dw * dw;
  }
  __shared__ float red[9][7];
  int wid = threadIdx.x >> 6, lane = threadIdx.x & 63;
#pragma unroll
  for (int i = 0; i < 7; ++i) {
    float p = wave_sum(s7[i]);
    if (lane == 0) red[wid][i] = p;
  }
  __syncthreads();
  if (threadIdx.x < 7) {
    float s = 0.f;
#pragma unroll
    for (int w = 0; w < 9; ++w) s += red[w][threadIdx.x];
    atomicAdd(&simo[threadIdx.x], expf(-0.5f * s) * (1.0f / 16384.0f));
  }
}

// FALLBACK abuild (invn-based).
__global__ __launch_bounds__(576) void abuild_sim(const float* __restrict__ basis,
                                                  const float* __restrict__ sf,
                                                  const float* __restrict__ task,
                                                  const float* __restrict__ invn,
                                                  unsigned short* __restrict__ Abf,
                                                  float* __restrict__ simo) {
  int b = blockIdx.x;
  int f = threadIdx.x;
  size_t row0 = (size_t)b * 8;
  float4 v[8];
#pragma unroll
  for (int n = 0; n < 8; ++n) {
    size_t row = row0 + n;
    float4 x;
    if (f < 32)       x = *(const float4*)(basis + row * 128 + f * 4);
    else if (f < 544) x = *(const float4*)(sf + row * 2048 + (f - 32) * 4);
    else {
      x = *(const float4*)(task + row * 128 + (f - 544) * 4);
      float s = invn[row];
      x.x *= s; x.y *= s; x.z *= s; x.w *= s;
    }
    v[n] = x;
    ushort4 o = make_ushort4(f2bf(x.x), f2bf(x.y), f2bf(x.z), f2bf(x.w));
    *(ushort4*)(Abf + row * 2304 + f * 4) = o;
  }
  float s7[7];
#pragma unroll
  for (int n = 1; n < 8; ++n) {
    float dx = v[n].x - v[n - 1].x, dy = v[n].y - v[n - 1].y;
    float dz = v[n].z - v[n - 1].z, dw = v[n].w - v[n - 1].w;
    s7[n - 1] = dx * dx + dy * dy + dz * dz + dw * dw;
  }
  __shared__ float red[9][7];
  int wid = threadIdx.x >> 6, lane = threadIdx.x & 63;
#pragma unroll
  for (int i = 0; i < 7; ++i) {
    float p = wave_sum(s7[i]);
    if (lane == 0) red[wid][i] = p;
  }
  __syncthreads();
  if (threadIdx.x < 7) {
    float s = 0.f;
#pragma unroll
    for (int w = 0; w < 9; ++w) s += red[w][threadIdx.x];
    atomicAdd(&simo[threadIdx.x], expf(-0.5f * s) * (1.0f / 16384.0f));
  }
}

// Combined keys+query MFMA GEMM (r8's proven 2-phase double-buffer body).
__global__ __launch_bounds__(256) void qk2(const unsigned short* __restrict__ Abf,
                                           const unsigned short* __restrict__ WkT,
                                           const unsigned short* __restrict__ WqT,
                                           const float* __restrict__ bias,
                                           const float* __restrict__ mask,
                                           float* __restrict__ km,
                                           float* __restrict__ query) {
  __shared__ unsigned short As[2 * 4096];
  __shared__ unsigned short Bs[2 * 4096];
  int bid = blockIdx.x;
  bool isq = bid >= 3072;
  int mt, nt;
  const unsigned short* WT;
  float* outp;
  if (!isq) {
    int swz = (bid & 7) * 384 + (bid >> 3);
    mt = swz / 3; nt = swz - mt * 3;
    WT = WkT; outp = km;
  } else {
    int q = bid - 3072;
    int swz = (q & 7) * 48 + (q >> 3);
    mt = swz / 3; nt = swz - mt * 3;
    WT = WqT; outp = query;
  }
  int tid = threadIdx.x;
  int wave = tid >> 6, lane = tid & 63;
  int wr = wave >> 1, wc = wave & 1;
  int m0g = mt * 128, n0g = nt * 128;

  int c_lo = wave * 128 + lane;
  int row_q0 = c_lo >> 2, kc_q0 = ((c_lo & 3) ^ ((row_q0 >> 1) & 3)) * 8;
  int c_hi = c_lo + 64;
  int row_q1 = c_hi >> 2, kc_q1 = ((c_hi & 3) ^ ((row_q1 >> 1) & 3)) * 8;
  size_t ga_q0 = isq ? (size_t)(m0g + row_q0) * 8 : (size_t)(m0g + row_q0);
  size_t ga_q1 = isq ? (size_t)(m0g + row_q1) * 8 : (size_t)(m0g + row_q1);
  const unsigned short* ag0 = Abf + ga_q0 * 2304 + kc_q0;
  const unsigned short* ag1 = Abf + ga_q1 * 2304 + kc_q1;
  const unsigned short* bg0 = WT + (size_t)(n0g + row_q0) * 2304 + kc_q0;
  const unsigned short* bg1 = WT + (size_t)(n0g + row_q1) * 2304 + kc_q1;
  int ldsoff0 = wave * 1024;
  int ldsoff1 = ldsoff0 + 512;

#define STAGE(ks, cur)                                                                   \
  do {                                                                                   \
    int _k0 = (ks) * 32;                                                                 \
    unsigned short* _a = As + (cur) * 4096;                                              \
    unsigned short* _b = Bs + (cur) * 4096;                                              \
    __builtin_amdgcn_global_load_lds(                                                    \
        (const __attribute__((address_space(1))) void*)(ag0 + _k0),                      \
        (__attribute__((address_space(3))) void*)(_a + ldsoff0), 16, 0, 0);              \
    __builtin_amdgcn_global_load_lds(                                                    \
        (const __attribute__((address_space(1))) void*)(ag1 + _k0),                      \
        (__attribute__((address_space(3))) void*)(_a + ldsoff1), 16, 0, 0);              \
    __builtin_amdgcn_global_load_lds(                                                    \
        (const __attribute__((address_space(1))) void*)(bg0 + _k0),                      \
        (__attribute__((address_space(3))) void*)(_b + ldsoff0), 16, 0, 0);              \
    __builtin_amdgcn_global_load_lds(                                                    \
        (const __attribute__((address_space(1))) void*)(bg1 + _k0),                      \
        (__attribute__((address_space(3))) void*)(_b + ldsoff1), 16, 0, 0);              \
  } while (0)

  f32x4 acc[4][4];
#pragma unroll
  for (int i = 0; i < 4; ++i)
#pragma unroll
    for (int j = 0; j < 4; ++j) acc[i][j] = (f32x4)(0.f);

  int la = lane & 15;
  int sl = (((lane >> 4) ^ ((la >> 1) & 3))) * 8;

  STAGE(0, 0);
  __syncthreads();
  int cur = 0;
  for (int ks = 0; ks < 72; ++ks) {
    if (ks < 71) STAGE(ks + 1, cur ^ 1);
    const unsigned short* aL = As + cur * 4096;
    const unsigned short* bL = Bs + cur * 4096;
    bf16x8 af[4], bf[4];
#pragma unroll
    for (int mi = 0; mi < 4; ++mi)
      af[mi] = *(const bf16x8*)(aL + (wr * 64 + mi * 16 + la) * 32 + sl);
#pragma unroll
    for (int ni = 0; ni < 4; ++ni)
      bf[ni] = *(const bf16x8*)(bL + (wc * 64 + ni * 16 + la) * 32 + sl);
#pragma unroll
    for (int mi = 0; mi < 4; ++mi)
#pragma unroll
      for (int ni = 0; ni < 4; ++ni)
        acc[mi][ni] = __builtin_amdgcn_mfma_f32_16x16x32_bf16(af[mi], bf[ni], acc[mi][ni], 0, 0, 0);
    __syncthreads();
    cur ^= 1;
  }
#undef STAGE

  int rq = lane >> 4;
#pragma unroll
  for (int mi = 0; mi < 4; ++mi) {
#pragma unroll
    for (int ni = 0; ni < 4; ++ni) {
      int colg = nt * 128 + wc * 64 + ni * 16 + la;
#pragma unroll
      for (int j = 0; j < 4; ++j) {
        int rowg = mt * 128 + wr * 64 + mi * 16 + rq * 4 + j;
        float v = acc[mi][ni][j];
        if (!isq)
          v = (v + bias[colg]) * mask[(size_t)rowg * 128 + (unsigned)colg / 3u];
        outp[(size_t)rowg * 384 + colg] = v;
      }
    }
  }
}

// FALLBACK attn (4 b per block, one wave per b).
__global__ __launch_bounds__(256) void attn_kernel4(const float* __restrict__ query,
                                                    const float* __restrict__ km,
                                                    float* __restrict__ logits,
                                                    float* __restrict__ wts) {
  int w = threadIdx.x >> 6, lane = threadIdx.x & 63;
  int b = blockIdx.x * 4 + w;
  float q[6];
#pragma unroll
  for (int j = 0; j < 6; ++j) q[j] = query[(size_t)b * 384 + lane + 64 * j];
  float lg[8];
#pragma unroll
  for (int n = 0; n < 8; ++n) {
    const float* kr = km + ((size_t)b * 8 + n) * 384;
    float p = 0.f;
#pragma unroll
    for (int j = 0; j < 6; ++j) p = fmaf(q[j], kr[lane + 64 * j], p);
    p = wave_sum(p);
    float l = p * 0.08838834764831845f;
    lg[n] = (l == 0.0f) ? -1e9f : l;
  }
  float m = lg[0];
#pragma unroll
  for (int i = 1; i < 8; ++i) m = fmaxf(m, lg[i]);
  float ex[8], s = 0.f;
#pragma unroll
  for (int i = 0; i < 8; ++i) { ex[i] = expf(lg[i] - m); s += ex[i]; }
  float inv = 1.0f / s;
  if (lane < 8) {
    float lv = lg[0], ev = ex[0];
#pragma unroll
    for (int i = 1; i < 8; ++i)
      if (lane == i) { lv = lg[i]; ev = ex[i]; }
    logits[(size_t)b * 8 + lane] = lv;
    wts[(size_t)b * 8 + lane] = ev * inv;
  }
}

// Values GEMM + fused attn-softmax + attend + q1. One block = one b.
// ABF=1/FATTN=1: A from Abf sf-section via global_load_lds+swizzle; B from WvT;
// attn logits/softmax computed in prologue (km+query reads), wts kept in LDS.
// ABF=0/FATTN=0: round-5 fallback (A from sf f32, B from Wv f32, wts from global).
template <int ABF, int FATTN>
__global__ __launch_bounds__(256) void v_gemm_attend(const float* __restrict__ sf,
                                                     const unsigned short* __restrict__ Abf,
                                                     const float* __restrict__ Wv,
                                                     const unsigned short* __restrict__ WvT,
                                                     const float* __restrict__ bv,
                                                     const float* __restrict__ wts,
                                                     const float* __restrict__ task,
                                                     const float* __restrict__ km,
                                                     const float* __restrict__ query,
                                                     float* __restrict__ logits,
                                                     float* __restrict__ wtso,
                                                     float* __restrict__ vm,
                                                     float* __restrict__ att,
                                                     float* __restrict__ q1) {
  __shared__ unsigned short As[2 * 4096];
  __shared__ unsigned short Bs[128 * 136];
  __shared__ float lgS[8];
  __shared__ float wtsS[8];
  float* attL = (float*)As;
  int bid = blockIdx.x;
  int swz = (bid & 7) * 2048 + (bid >> 3);
  int b = swz;
  size_t m0 = (size_t)swz * 128;
  int tid = threadIdx.x;
  int wave = tid >> 6, lane = tid & 63;
  int wr = wave >> 1, wc = wave & 1;
  int r = tid >> 1, h = tid & 1;
  int la = lane & 15, lkq = lane >> 4;
  int sl = ((lkq ^ ((la >> 1) & 3))) * 8;

  if (ABF) {
#pragma unroll
    for (int q = 0; q < 8; ++q) {
      bf16x8 v = *(const bf16x8*)(WvT + (size_t)r * 128 + h * 64 + q * 8);
      *(bf16x8*)(Bs + r * 136 + h * 64 + q * 8) = v;
    }
  } else {
#pragma unroll
    for (int q = 0; q < 16; ++q) {
      int flat = q * 256 + tid;
      int k = flat >> 5;
      int n4 = (flat & 31) * 4;
      float4 v = *(const float4*)(Wv + (size_t)k * 128 + n4);
      Bs[(n4 + 0) * 136 + k] = f2bf(v.x);
      Bs[(n4 + 1) * 136 + k] = f2bf(v.y);
      Bs[(n4 + 2) * 136 + k] = f2bf(v.z);
      Bs[(n4 + 3) * 136 + k] = f2bf(v.w);
    }
  }

  const unsigned short *ap0 = nullptr, *ap1 = nullptr;
  int ldsA0 = wave * 1024, ldsA1 = ldsA0 + 512;
  if (ABF) {
    int p0 = wave * 128 + lane;
    int tr0 = p0 >> 2, ds0 = (p0 & 3) ^ ((tr0 >> 1) & 3);
    int p1 = p0 + 64;
    int tr1 = p1 >> 2, ds1 = (p1 & 3) ^ ((tr1 >> 1) & 3);
    ap0 = Abf + ((size_t)b * 8 + (tr0 >> 4)) * 2304 + 128 + (tr0 & 15) * 128 + ds0 * 8;
    ap1 = Abf + ((size_t)b * 8 + (tr1 >> 4)) * 2304 + 128 + (tr1 & 15) * 128 + ds1 * 8;
    __builtin_amdgcn_global_load_lds(
        (const __attribute__((address_space(1))) void*)(ap0),
        (__attribute__((address_space(3))) void*)(As + ldsA0), 16, 0, 0);
    __builtin_amdgcn_global_load_lds(
        (const __attribute__((address_space(1))) void*)(ap1),
        (__attribute__((address_space(3))) void*)(As + ldsA1), 16, 0, 0);
  }

  if (FATTN) {
    // fused attn: wave w computes logits rows n = 2w, 2w+1 (global km/query reads
    // overlap the in-flight staging above; no extra barrier needed)
    const float* qr = query + (size_t)b * 384;
#pragma unroll
    for (int i = 0; i < 2; ++i) {
      int n = wave * 2 + i;
      const float* kr = km + ((size_t)b * 8 + n) * 384;
      float p = 0.f;
#pragma unroll
      for (int j = 0; j < 6; ++j) p = fmaf(qr[lane + 64 * j], kr[lane + 64 * j], p);
      p = wave_sum(p);
      if (lane == 0) {
        float l = p * 0.08838834764831845f;  // 1/sqrt(128)
        l = (l == 0.0f) ? -1e9f : l;
        lgS[n] = l;
        logits[(size_t)b * 8 + n] = l;
      }
    }
  }

  f32x4 acc[4][4];
#pragma unroll
  for (int i = 0; i < 4; ++i)
#pragma unroll
    for (int j = 0; j < 4; ++j) acc[i][j] = (f32x4)(0.f);

  if (ABF || FATTN) __syncthreads();  // seals B ds_writes + A gload(0) + lgS

  if (FATTN) {
    if (tid < 8) {
      float m = lgS[0];
#pragma unroll
      for (int i = 1; i < 8; ++i) m = fmaxf(m, lgS[i]);
      float s = 0.f;
#pragma unroll
      for (int i = 0; i < 8; ++i) s += expf(lgS[i] - m);
      float w = expf(lgS[tid] - m) / s;
      wtsS[tid] = w;                      // sealed by the K-loop barriers below
      wtso[(size_t)b * 8 + tid] = w;
    }
  }

  int cur = 0;
  for (int ks = 0; ks < 4; ++ks) {
    int k0 = ks * 32;
    if (ABF) {
      if (ks < 3) {
        __builtin_amdgcn_global_load_lds(
            (const __attribute__((address_space(1))) void*)(ap0 + k0 + 32),
            (__attribute__((address_space(3))) void*)(As + (cur ^ 1) * 4096 + ldsA0), 16, 0, 0);
        __builtin_amdgcn_global_load_lds(
            (const __attribute__((address_space(1))) void*)(ap1 + k0 + 32),
            (__attribute__((address_space(3))) void*)(As + (cur ^ 1) * 4096 + ldsA1), 16, 0, 0);
      }
    } else {
      const float* ap = sf + (m0 + r) * 128 + k0 + h * 16;
      float4 v0 = *(const float4*)(ap);
      float4 v1 = *(const float4*)(ap + 4);
      float4 v2 = *(const float4*)(ap + 8);
      float4 v3 = *(const float4*)(ap + 12);
      ushort4 p0 = make_ushort4(f2bf(v0.x), f2bf(v0.y), f2bf(v0.z), f2bf(v0.w));
      ushort4 p1 = make_ushort4(f2bf(v1.x), f2bf(v1.y), f2bf(v1.z), f2bf(v1.w));
      ushort4 p2 = make_ushort4(f2bf(v2.x), f2bf(v2.y), f2bf(v2.z), f2bf(v2.w));
      ushort4 p3 = make_ushort4(f2bf(v3.x), f2bf(v3.y), f2bf(v3.z), f2bf(v3.w));
      *(ushort4*)(As + r * 40 + h * 16)      = p0;
      *(ushort4*)(As + r * 40 + h * 16 + 4)  = p1;
      *(ushort4*)(As + r * 40 + h * 16 + 8)  = p2;
      *(ushort4*)(As + r * 40 + h * 16 + 12) = p3;
      __syncthreads();
    }
    const unsigned short* aL = ABF ? (As + cur * 4096) : As;
    bf16x8 af[4], bfr[4];
#pragma unroll
    for (int mi = 0; mi < 4; ++mi) {
      int rowl = wr * 64 + mi * 16 + la;
      af[mi] = ABF ? *(const bf16x8*)(aL + rowl * 32 + sl)
                   : *(const bf16x8*)(aL + rowl * 40 + lkq * 8);
    }
#pragma unroll
    for (int ni = 0; ni < 4; ++ni)
      bfr[ni] = *(const bf16x8*)(Bs + (wc * 64 + ni * 16 + la) * 136 + k0 + lkq * 8);
#pragma unroll
    for (int mi = 0; mi < 4; ++mi)
#pragma unroll
      for (int ni = 0; ni < 4; ++ni)
        acc[mi][ni] = __builtin_amdgcn_mfma_f32_16x16x32_bf16(af[mi], bfr[ni], acc[mi][ni], 0, 0, 0);
    __syncthreads();
    cur ^= 1;
  }

  // epilogue: vm write + weighted partials over mi (n = wr*4+mi)
  float w4[4];
#pragma unroll
  for (int mi = 0; mi < 4; ++mi)
    w4[mi] = FATTN ? wtsS[wr * 4 + mi] : wts[(size_t)b * 8 + wr * 4 + mi];
  float pacc[4][4];
#pragma unroll
  for (int ni = 0; ni < 4; ++ni)
#pragma unroll
    for (int j = 0; j < 4; ++j) pacc[ni][j] = 0.f;
#pragma unroll
  for (int mi = 0; mi < 4; ++mi) {
#pragma unroll
    for (int ni = 0; ni < 4; ++ni) {
      int colg = wc * 64 + ni * 16 + la;
      float bb = bv[colg];
#pragma unroll
      for (int j = 0; j < 4; ++j) {
        size_t rowg = m0 + wr * 64 + mi * 16 + lkq * 4 + j;
        float v = acc[mi][ni][j] + bb;
        vm[rowg * 128 + colg] = v;
        pacc[ni][j] = fmaf(w4[mi], v, pacc[ni][j]);
      }
    }
  }
  if (wr == 0) {
#pragma unroll
    for (int ni = 0; ni < 4; ++ni)
#pragma unroll
      for (int j = 0; j < 4; ++j)
        attL[(lkq * 4 + j) * 132 + wc * 64 + ni * 16 + la] = pacc[ni][j];
  }
  __syncthreads();
  if (wr == 1) {
#pragma unroll
    for (int ni = 0; ni < 4; ++ni)
#pragma unroll
      for (int j = 0; j < 4; ++j)
        attL[(lkq * 4 + j) * 132 + wc * 64 + ni * 16 + la] += pacc[ni][j];
  }
  __syncthreads();
#pragma unroll
  for (int i = 0; i < 2; ++i) {
    int fidx = tid + i * 256;
    int a = fidx >> 5, c = (fidx & 31) * 4;
    f32x4 vv = *(const f32x4*)(attL + a * 132 + c);
    *(f32x4*)(att + (size_t)b * 2048 + a * 128 + c) = vv;
  }
  for (int j = wave; j < 16; j += 4) {
    float p = task[(size_t)b * 1024 + lane] * attL[j * 132 + lane]
            + task[(size_t)b * 1024 + 64 + lane] * attL[j * 132 + 64 + lane];
    p = wave_sum(p);
    if (lane == 0) q1[(size_t)b * 16 + j] = p;
  }
}

extern "C" void kernel_launch(void* const* d_in, const int* in_sizes, int n_in,
                              void* d_out, int out_size, void* d_ws, size_t ws_size,
                              hipStream_t stream) {
  const float* basis = (const float*)d_in[0];
  const float* sf    = (const float*)d_in[1];
  const float* task  = (const float*)d_in[2];
  const float* mask  = (const float*)d_in[3];
  const float* Wq    = (const float*)d_in[4];
  const float* Wk    = (const float*)d_in[5];
  const float* bk    = (const float*)d_in[6];
  const float* Wv    = (const float*)d_in[7];
  const float* bv    = (const float*)d_in[8];

  float* out  = (float*)d_out;
  float* q1   = out;
  float* att  = out + OFF_ATT;
  float* logi = out + OFF_LOG;
  float* wts  = out + OFF_W;
  float* km   = out + OFF_KM;
  float* vm   = out + OFF_VM;
  float* simo = out + OFF_SIM;

  // d_ws layout (preferred path): Abf | WkT | WqT | WvT | query | invn = ~634MB.
  constexpr size_t WS_NEED = 603979776ull + 1769472ull + 1769472ull + 32768ull +
                             25165824ull + 524288ull;
  bool usews = ws_size >= WS_NEED;

  unsigned short *Abf, *WkT, *WqT, *WvT = nullptr;
  float *query, *invn;
  if (usews) {
    unsigned char* ws = (unsigned char*)d_ws;
    Abf   = (unsigned short*)ws;
    WkT   = (unsigned short*)(ws + 603979776ull);
    WqT   = (unsigned short*)(ws + 605749248ull);
    WvT   = (unsigned short*)(ws + 607518720ull);
    query = (float*)(ws + 607551488ull);
    invn  = (float*)(ws + 632717312ull);

    hipMemsetAsync(simo, 0, 7 * sizeof(float), stream);
    wprep3<<<436, 256, 0, stream>>>(Wk, Wq, Wv, WkT, WqT, WvT);
    abuild_sim_fn<<<16384, 576, 0, stream>>>(basis, sf, task, Abf, simo);
    // combined keys (3072 blocks) + query (384 blocks), r8 2-phase body
    qk2<<<3456, 256, 0, stream>>>(Abf, WkT, WqT, bk, mask, km, query);
    // values GEMM + fused attn/softmax/attend/q1
    v_gemm_attend<1, 1><<<16384, 256, 0, stream>>>(sf, Abf, Wv, WvT, bv, nullptr,
                                                   task, km, query, logi, wts,
                                                   vm, att, q1);
  } else {
    // fallback: r11 pipeline with output-region stashes
    query = att;
    invn  = att + 6291456;
    WkT   = (unsigned short*)(att + 6422528);
    WqT   = WkT + 884736;
    Abf   = (unsigned short*)vm;

    norm_kernel<<<32768, 256, 0, stream>>>(task, invn, simo);
    wprep_t<<<216, 256, 0, stream>>>(Wk, WkT, 2304, 384);
    wprep_t<<<216, 256, 0, stream>>>(Wq, WqT, 2304, 384);
    abuild_sim<<<16384, 576, 0, stream>>>(basis, sf, task, invn, Abf, simo);
    qk2<<<3456, 256, 0, stream>>>(Abf, WkT, WqT, bk, mask, km, query);
    attn_kernel4<<<4096, 256, 0, stream>>>(query, km, logi, wts);
    v_gemm_attend<0, 0><<<16384, 256, 0, stream>>>(sf, nullptr, Wv, nullptr, bv, wts,
                                                   task, nullptr, nullptr, nullptr,
                                                   nullptr, vm, att, q1);
  }
}

// Round 13
// 1222.169 us; speedup vs baseline: 1.2351x; 1.0271x over previous
//
#include <hip/hip_runtime.h>
#include <hip/hip_bf16.h>
#include <math.h>

// B=16384, NB=8, NA=16, D=128, IN_DIM=2304, QK_DIM=384, V_DIM=128
static constexpr size_t OFF_ATT = 262144;      // attended_sf (33,554,432 f32)
static constexpr size_t OFF_LOG = 33816576;    // attn_logits
static constexpr size_t OFF_W   = 33947648;    // attention_weights
static constexpr size_t OFF_KM  = 34078720;    // keys_masked
static constexpr size_t OFF_VM  = 84410368;    // values_masked (268,435,456 f32)
static constexpr size_t OFF_SIM = 352845824;   // sim (7)

typedef short bf16x8 __attribute__((ext_vector_type(8)));
typedef float f32x4 __attribute__((ext_vector_type(4)));

__device__ inline unsigned short f2bf(float f) {
  union { float f; unsigned u; } x; x.f = f;
  unsigned r = x.u + 0x7FFFu + ((x.u >> 16) & 1u);  // RNE
  return (unsigned short)(r >> 16);
}

__device__ inline float wave_sum(float v) {
#pragma unroll
  for (int o = 32; o > 0; o >>= 1) v += __shfl_xor(v, o, 64);
  return v;
}

// FALLBACK only: one wave per (b,n) row inverse L2 norm + zero sim slots.
__global__ void norm_kernel(const float* __restrict__ task, float* __restrict__ invn,
                            float* __restrict__ simo) {
  int idx = blockIdx.x * 4 + (threadIdx.x >> 6);
  int lane = threadIdx.x & 63;
  float t0 = task[(size_t)idx * 128 + lane];
  float t1 = task[(size_t)idx * 128 + 64 + lane];
  float s = wave_sum(t0 * t0 + t1 * t1);
  if (lane == 0) invn[idx] = rsqrtf(s);
  if (blockIdx.x == 0 && threadIdx.x < 7) simo[threadIdx.x] = 0.0f;
}

// Tiled transpose+cvt for all three weights in one dispatch (436 blocks).
__global__ void wprep3(const float* __restrict__ Wk, const float* __restrict__ Wq,
                       const float* __restrict__ Wv,
                       unsigned short* __restrict__ WkT, unsigned short* __restrict__ WqT,
                       unsigned short* __restrict__ WvT) {
  int bb = blockIdx.x;
  const float* W; unsigned short* WT; int K, N, b2;
  if (bb < 216)      { W = Wk; WT = WkT; K = 2304; N = 384; b2 = bb; }
  else if (bb < 432) { W = Wq; WT = WqT; K = 2304; N = 384; b2 = bb - 216; }
  else               { W = Wv; WT = WvT; K = 128;  N = 128; b2 = bb - 432; }
  int ntn = N >> 6;
  int kt = b2 / ntn, nt = b2 % ntn;
  int k0 = kt * 64, n0 = nt * 64;
  __shared__ float t[64][65];
  int tid = threadIdx.x;
  int r = tid >> 2, c0 = (tid & 3) * 16;
#pragma unroll
  for (int q = 0; q < 4; ++q) {
    float4 v = *(const float4*)(W + (size_t)(k0 + r) * N + n0 + c0 + q * 4);
    t[r][c0 + q * 4 + 0] = v.x; t[r][c0 + q * 4 + 1] = v.y;
    t[r][c0 + q * 4 + 2] = v.z; t[r][c0 + q * 4 + 3] = v.w;
  }
  __syncthreads();
  int n = tid >> 2, kc0 = (tid & 3) * 16;
#pragma unroll
  for (int q = 0; q < 4; ++q) {
    int kc = kc0 + q * 4;
    ushort4 o = make_ushort4(f2bf(t[kc + 0][n]), f2bf(t[kc + 1][n]),
                             f2bf(t[kc + 2][n]), f2bf(t[kc + 3][n]));
    *(ushort4*)(WT + (size_t)(n0 + n) * K + k0 + kc) = o;
  }
}

// Legacy wprep (fallback path).
__global__ void wprep_t(const float* __restrict__ W, unsigned short* __restrict__ WT,
                        int K, int N) {
  int ntn = N >> 6;
  int kt = blockIdx.x / ntn, nt = blockIdx.x % ntn;
  int k0 = kt * 64, n0 = nt * 64;
  __shared__ float t[64][65];
  int tid = threadIdx.x;
  int r = tid >> 2, c0 = (tid & 3) * 16;
#pragma unroll
  for (int q = 0; q < 4; ++q) {
    float4 v = *(const float4*)(W + (size_t)(k0 + r) * N + n0 + c0 + q * 4);
    t[r][c0 + q * 4 + 0] = v.x; t[r][c0 + q * 4 + 1] = v.y;
    t[r][c0 + q * 4 + 2] = v.z; t[r][c0 + q * 4 + 3] = v.w;
  }
  __syncthreads();
  int n = tid >> 2, kc0 = (tid & 3) * 16;
#pragma unroll
  for (int q = 0; q < 4; ++q) {
    int kc = kc0 + q * 4;
    ushort4 o = make_ushort4(f2bf(t[kc + 0][n]), f2bf(t[kc + 1][n]),
                             f2bf(t[kc + 2][n]), f2bf(t[kc + 3][n]));
    *(ushort4*)(WT + (size_t)(n0 + n) * K + k0 + kc) = o;
  }
}

// One block (576 thr) per b with FUSED task-norm.
__global__ __launch_bounds__(576) void abuild_sim_fn(const float* __restrict__ basis,
                                                     const float* __restrict__ sf,
                                                     const float* __restrict__ task,
                                                     unsigned short* __restrict__ Abf,
                                                     float* __restrict__ simo) {
  int b = blockIdx.x;
  int f = threadIdx.x;  // 0..575
  size_t row0 = (size_t)b * 8;
  float4 v[8];
  if (f >= 544) {
    float ss[8];
#pragma unroll
    for (int n = 0; n < 8; ++n) {
      float4 x = *(const float4*)(task + (row0 + n) * 128 + (f - 544) * 4);
      v[n] = x;
      ss[n] = x.x * x.x + x.y * x.y + x.z * x.z + x.w * x.w;
    }
#pragma unroll
    for (int n = 0; n < 8; ++n) {
#pragma unroll
      for (int o = 16; o > 0; o >>= 1) ss[n] += __shfl_xor(ss[n], o, 64);
      float iv = rsqrtf(ss[n]);
      v[n].x *= iv; v[n].y *= iv; v[n].z *= iv; v[n].w *= iv;
    }
  } else if (f < 32) {
#pragma unroll
    for (int n = 0; n < 8; ++n) v[n] = *(const float4*)(basis + (row0 + n) * 128 + f * 4);
  } else {
#pragma unroll
    for (int n = 0; n < 8; ++n) v[n] = *(const float4*)(sf + (row0 + n) * 2048 + (f - 32) * 4);
  }
#pragma unroll
  for (int n = 0; n < 8; ++n) {
    ushort4 o = make_ushort4(f2bf(v[n].x), f2bf(v[n].y), f2bf(v[n].z), f2bf(v[n].w));
    *(ushort4*)(Abf + (row0 + n) * 2304 + f * 4) = o;
  }
  float s7[7];
#pragma unroll
  for (int n = 1; n < 8; ++n) {
    float dx = v[n].x - v[n - 1].x, dy = v[n].y - v[n - 1].y;
    float dz = v[n].z - v[n - 1].z, dw = v[n].w - v[n - 1].w;
    s7[n - 1] = dx * dx + dy * dy + dz * dz + dw * dw;
  }
  __shared__ float red[9][7];
  int wid = threadIdx.x >> 6, lane = threadIdx.x & 63;
#pragma unroll
  for (int i = 0; i < 7; ++i) {
    float p = wave_sum(s7[i]);
    if (lane == 0) red[wid][i] = p;
  }
  __syncthreads();
  if (threadIdx.x < 7) {
    float s = 0.f;
#pragma unroll
    for (int w = 0; w < 9; ++w) s += red[w][threadIdx.x];
    atomicAdd(&simo[threadIdx.x], expf(-0.5f * s) * (1.0f / 16384.0f));
  }
}

// FALLBACK abuild (invn-based).
__global__ __launch_bounds__(576) void abuild_sim(const float* __restrict__ basis,
                                                  const float* __restrict__ sf,
                                                  const float* __restrict__ task,
                                                  const float* __restrict__ invn,
                                                  unsigned short* __restrict__ Abf,
                                                  float* __restrict__ simo) {
  int b = blockIdx.x;
  int f = threadIdx.x;
  size_t row0 = (size_t)b * 8;
  float4 v[8];
#pragma unroll
  for (int n = 0; n < 8; ++n) {
    size_t row = row0 + n;
    float4 x;
    if (f < 32)       x = *(const float4*)(basis + row * 128 + f * 4);
    else if (f < 544) x = *(const float4*)(sf + row * 2048 + (f - 32) * 4);
    else {
      x = *(const float4*)(task + row * 128 + (f - 544) * 4);
      float s = invn[row];
      x.x *= s; x.y *= s; x.z *= s; x.w *= s;
    }
    v[n] = x;
    ushort4 o = make_ushort4(f2bf(x.x), f2bf(x.y), f2bf(x.z), f2bf(x.w));
    *(ushort4*)(Abf + row * 2304 + f * 4) = o;
  }
  float s7[7];
#pragma unroll
  for (int n = 1; n < 8; ++n) {
    float dx = v[n].x - v[n - 1].x, dy = v[n].y - v[n - 1].y;
    float dz = v[n].z - v[n - 1].z, dw = v[n].w - v[n - 1].w;
    s7[n - 1] = dx * dx + dy * dy + dz * dz + dw * dw;
  }
  __shared__ float red[9][7];
  int wid = threadIdx.x >> 6, lane = threadIdx.x & 63;
#pragma unroll
  for (int i = 0; i < 7; ++i) {
    float p = wave_sum(s7[i]);
    if (lane == 0) red[wid][i] = p;
  }
  __syncthreads();
  if (threadIdx.x < 7) {
    float s = 0.f;
#pragma unroll
    for (int w = 0; w < 9; ++w) s += red[w][threadIdx.x];
    atomicAdd(&simo[threadIdx.x], expf(-0.5f * s) * (1.0f / 16384.0f));
  }
}

// Combined keys+query GEMM, 512 threads / 8 waves, 128x128 tile, BK=32,
// TRIPLE-buffered (48KB) counted-vmcnt pipeline (r10 schedule, r8 swizzle):
// stage(t) issued at iter t-2, vmcnt(2) before raw s_barrier publishes stage(t+1)
// while stage(t+2)'s 2 loads stay in flight across the barrier. 3 blocks/CU ->
// 24 waves/CU (fixes r10's 12-wave occupancy regression).
__global__ __launch_bounds__(512) void qk512(const unsigned short* __restrict__ Abf,
                                             const unsigned short* __restrict__ WkT,
                                             const unsigned short* __restrict__ WqT,
                                             const float* __restrict__ bias,
                                             const float* __restrict__ mask,
                                             float* __restrict__ km,
                                             float* __restrict__ query) {
  __shared__ unsigned short As[3 * 4096];
  __shared__ unsigned short Bs[3 * 4096];
  int bid = blockIdx.x;
  bool isq = bid >= 3072;
  int mt, nt;
  const unsigned short* WT;
  float* outp;
  if (!isq) {
    int swz = (bid & 7) * 384 + (bid >> 3);
    mt = swz / 3; nt = swz - mt * 3;
    WT = WkT; outp = km;
  } else {
    int q = bid - 3072;
    int swz = (q & 7) * 48 + (q >> 3);
    mt = swz / 3; nt = swz - mt * 3;
    WT = WqT; outp = query;
  }
  int tid = threadIdx.x;
  int wave = tid >> 6, lane = tid & 63;
  int wr = wave >> 2, wc = wave & 3;   // 2M x 4N wave grid; wave tile 64x32
  int m0g = mt * 128, n0g = nt * 128;

  // staging: one 16B chunk per thread per operand. chunk c = tid; row = c>>2;
  // global k-slot pre-swizzled by the involution slot^((row>>1)&3)
  int c = tid;
  int arow = c >> 2, akc = ((c & 3) ^ ((arow >> 1) & 3)) * 8;
  size_t ga = isq ? (size_t)(m0g + arow) * 8 : (size_t)(m0g + arow);
  const unsigned short* ag = Abf + ga * 2304 + akc;
  const unsigned short* bg = WT + (size_t)(n0g + arow) * 2304 + akc;
  int ldsoff = wave * 512;  // elements; wave-uniform (HW adds lane*16B)

#define STAGE(ks, buf)                                                                   \
  do {                                                                                   \
    int _k0 = (ks) * 32;                                                                 \
    __builtin_amdgcn_global_load_lds(                                                    \
        (const __attribute__((address_space(1))) void*)(ag + _k0),                       \
        (__attribute__((address_space(3))) void*)(As + (buf) * 4096 + ldsoff),           \
        16, 0, 0);                                                                       \
    __builtin_amdgcn_global_load_lds(                                                    \
        (const __attribute__((address_space(1))) void*)(bg + _k0),                       \
        (__attribute__((address_space(3))) void*)(Bs + (buf) * 4096 + ldsoff),           \
        16, 0, 0);                                                                       \
  } while (0)

  f32x4 acc[4][2];
#pragma unroll
  for (int i = 0; i < 4; ++i)
#pragma unroll
    for (int j = 0; j < 2; ++j) acc[i][j] = (f32x4)(0.f);

  int la = lane & 15;
  int sl = (((lane >> 4) ^ ((la >> 1) & 3))) * 8;  // swizzled k-slot for reads

  // prologue: two stages in flight; publish stage(0)
  STAGE(0, 0);
  STAGE(1, 1);
  asm volatile("s_waitcnt vmcnt(2)" ::: "memory");   // stage(0) landed (mine)
  __builtin_amdgcn_s_barrier();                      // stage(0) landed (all waves)
  asm volatile("" ::: "memory");

  int rd = 0, st = 2;
  for (int ks = 0; ks < 72; ++ks) {
    if (ks < 70) STAGE(ks + 2, st);  // writes buf read at ks-1 (sealed by barrier(ks-1))
    const unsigned short* aL = As + rd * 4096;
    const unsigned short* bL = Bs + rd * 4096;
    bf16x8 af[4], bf[2];
#pragma unroll
    for (int mi = 0; mi < 4; ++mi)
      af[mi] = *(const bf16x8*)(aL + (wr * 64 + mi * 16 + la) * 32 + sl);
#pragma unroll
    for (int ni = 0; ni < 2; ++ni)
      bf[ni] = *(const bf16x8*)(bL + (wc * 32 + ni * 16 + la) * 32 + sl);
#pragma unroll
    for (int mi = 0; mi < 4; ++mi)
#pragma unroll
      for (int ni = 0; ni < 2; ++ni)
        acc[mi][ni] = __builtin_amdgcn_mfma_f32_16x16x32_bf16(af[mi], bf[ni], acc[mi][ni], 0, 0, 0);
    // publish stage(ks+1): wait until only stage(ks+2)'s 2 loads remain in flight
    if (ks < 70) asm volatile("s_waitcnt vmcnt(2)" ::: "memory");
    else         asm volatile("s_waitcnt vmcnt(0)" ::: "memory");
    __builtin_amdgcn_s_barrier();
    asm volatile("" ::: "memory");
    rd = (rd == 2) ? 0 : rd + 1;
    st = (st == 2) ? 0 : st + 1;
  }
#undef STAGE

  int rq = lane >> 4;
#pragma unroll
  for (int mi = 0; mi < 4; ++mi) {
#pragma unroll
    for (int ni = 0; ni < 2; ++ni) {
      int colg = nt * 128 + wc * 32 + ni * 16 + la;
#pragma unroll
      for (int j = 0; j < 4; ++j) {
        int rowg = mt * 128 + wr * 64 + mi * 16 + rq * 4 + j;
        float v = acc[mi][ni][j];
        if (!isq)
          v = (v + bias[colg]) * mask[(size_t)rowg * 128 + (unsigned)colg / 3u];
        outp[(size_t)rowg * 384 + colg] = v;
      }
    }
  }
}

// FALLBACK qk2 (256 threads, r8 2-phase body).
__global__ __launch_bounds__(256) void qk2(const unsigned short* __restrict__ Abf,
                                           const unsigned short* __restrict__ WkT,
                                           const unsigned short* __restrict__ WqT,
                                           const float* __restrict__ bias,
                                           const float* __restrict__ mask,
                                           float* __restrict__ km,
                                           float* __restrict__ query) {
  __shared__ unsigned short As[2 * 4096];
  __shared__ unsigned short Bs[2 * 4096];
  int bid = blockIdx.x;
  bool isq = bid >= 3072;
  int mt, nt;
  const unsigned short* WT;
  float* outp;
  if (!isq) {
    int swz = (bid & 7) * 384 + (bid >> 3);
    mt = swz / 3; nt = swz - mt * 3;
    WT = WkT; outp = km;
  } else {
    int q = bid - 3072;
    int swz = (q & 7) * 48 + (q >> 3);
    mt = swz / 3; nt = swz - mt * 3;
    WT = WqT; outp = query;
  }
  int tid = threadIdx.x;
  int wave = tid >> 6, lane = tid & 63;
  int wr = wave >> 1, wc = wave & 1;
  int m0g = mt * 128, n0g = nt * 128;

  int c_lo = wave * 128 + lane;
  int row_q0 = c_lo >> 2, kc_q0 = ((c_lo & 3) ^ ((row_q0 >> 1) & 3)) * 8;
  int c_hi = c_lo + 64;
  int row_q1 = c_hi >> 2, kc_q1 = ((c_hi & 3) ^ ((row_q1 >> 1) & 3)) * 8;
  size_t ga_q0 = isq ? (size_t)(m0g + row_q0) * 8 : (size_t)(m0g + row_q0);
  size_t ga_q1 = isq ? (size_t)(m0g + row_q1) * 8 : (size_t)(m0g + row_q1);
  const unsigned short* ag0 = Abf + ga_q0 * 2304 + kc_q0;
  const unsigned short* ag1 = Abf + ga_q1 * 2304 + kc_q1;
  const unsigned short* bg0 = WT + (size_t)(n0g + row_q0) * 2304 + kc_q0;
  const unsigned short* bg1 = WT + (size_t)(n0g + row_q1) * 2304 + kc_q1;
  int ldsoff0 = wave * 1024;
  int ldsoff1 = ldsoff0 + 512;

#define STAGE(ks, cur)                                                                   \
  do {                                                                                   \
    int _k0 = (ks) * 32;                                                                 \
    unsigned short* _a = As + (cur) * 4096;                                              \
    unsigned short* _b = Bs + (cur) * 4096;                                              \
    __builtin_amdgcn_global_load_lds(                                                    \
        (const __attribute__((address_space(1))) void*)(ag0 + _k0),                      \
        (__attribute__((address_space(3))) void*)(_a + ldsoff0), 16, 0, 0);              \
    __builtin_amdgcn_global_load_lds(                                                    \
        (const __attribute__((address_space(1))) void*)(ag1 + _k0),                      \
        (__attribute__((address_space(3))) void*)(_a + ldsoff1), 16, 0, 0);              \
    __builtin_amdgcn_global_load_lds(                                                    \
        (const __attribute__((address_space(1))) void*)(bg0 + _k0),                      \
        (__attribute__((address_space(3))) void*)(_b + ldsoff0), 16, 0, 0);              \
    __builtin_amdgcn_global_load_lds(                                                    \
        (const __attribute__((address_space(1))) void*)(bg1 + _k0),                      \
        (__attribute__((address_space(3))) void*)(_b + ldsoff1), 16, 0, 0);              \
  } while (0)

  f32x4 acc[4][4];
#pragma unroll
  for (int i = 0; i < 4; ++i)
#pragma unroll
    for (int j = 0; j < 4; ++j) acc[i][j] = (f32x4)(0.f);

  int la = lane & 15;
  int sl = (((lane >> 4) ^ ((la >> 1) & 3))) * 8;

  STAGE(0, 0);
  __syncthreads();
  int cur = 0;
  for (int ks = 0; ks < 72; ++ks) {
    if (ks < 71) STAGE(ks + 1, cur ^ 1);
    const unsigned short* aL = As + cur * 4096;
    const unsigned short* bL = Bs + cur * 4096;
    bf16x8 af[4], bf[4];
#pragma unroll
    for (int mi = 0; mi < 4; ++mi)
      af[mi] = *(const bf16x8*)(aL + (wr * 64 + mi * 16 + la) * 32 + sl);
#pragma unroll
    for (int ni = 0; ni < 4; ++ni)
      bf[ni] = *(const bf16x8*)(bL + (wc * 64 + ni * 16 + la) * 32 + sl);
#pragma unroll
    for (int mi = 0; mi < 4; ++mi)
#pragma unroll
      for (int ni = 0; ni < 4; ++ni)
        acc[mi][ni] = __builtin_amdgcn_mfma_f32_16x16x32_bf16(af[mi], bf[ni], acc[mi][ni], 0, 0, 0);
    __syncthreads();
    cur ^= 1;
  }
#undef STAGE

  int rq = lane >> 4;
#pragma unroll
  for (int mi = 0; mi < 4; ++mi) {
#pragma unroll
    for (int ni = 0; ni < 4; ++ni) {
      int colg = nt * 128 + wc * 64 + ni * 16 + la;
#pragma unroll
      for (int j = 0; j < 4; ++j) {
        int rowg = mt * 128 + wr * 64 + mi * 16 + rq * 4 + j;
        float v = acc[mi][ni][j];
        if (!isq)
          v = (v + bias[colg]) * mask[(size_t)rowg * 128 + (unsigned)colg / 3u];
        outp[(size_t)rowg * 384 + colg] = v;
      }
    }
  }
}

// FALLBACK attn (4 b per block, one wave per b).
__global__ __launch_bounds__(256) void attn_kernel4(const float* __restrict__ query,
                                                    const float* __restrict__ km,
                                                    float* __restrict__ logits,
                                                    float* __restrict__ wts) {
  int w = threadIdx.x >> 6, lane = threadIdx.x & 63;
  int b = blockIdx.x * 4 + w;
  float q[6];
#pragma unroll
  for (int j = 0; j < 6; ++j) q[j] = query[(size_t)b * 384 + lane + 64 * j];
  float lg[8];
#pragma unroll
  for (int n = 0; n < 8; ++n) {
    const float* kr = km + ((size_t)b * 8 + n) * 384;
    float p = 0.f;
#pragma unroll
    for (int j = 0; j < 6; ++j) p = fmaf(q[j], kr[lane + 64 * j], p);
    p = wave_sum(p);
    float l = p * 0.08838834764831845f;
    lg[n] = (l == 0.0f) ? -1e9f : l;
  }
  float m = lg[0];
#pragma unroll
  for (int i = 1; i < 8; ++i) m = fmaxf(m, lg[i]);
  float ex[8], s = 0.f;
#pragma unroll
  for (int i = 0; i < 8; ++i) { ex[i] = expf(lg[i] - m); s += ex[i]; }
  float inv = 1.0f / s;
  if (lane < 8) {
    float lv = lg[0], ev = ex[0];
#pragma unroll
    for (int i = 1; i < 8; ++i)
      if (lane == i) { lv = lg[i]; ev = ex[i]; }
    logits[(size_t)b * 8 + lane] = lv;
    wts[(size_t)b * 8 + lane] = ev * inv;
  }
}

// Values GEMM + fused attn-softmax + attend + q1. One block = one b.
template <int ABF, int FATTN>
__global__ __launch_bounds__(256) void v_gemm_attend(const float* __restrict__ sf,
                                                     const unsigned short* __restrict__ Abf,
                                                     const float* __restrict__ Wv,
                                                     const unsigned short* __restrict__ WvT,
                                                     const float* __restrict__ bv,
                                                     const float* __restrict__ wts,
                                                     const float* __restrict__ task,
                                                     const float* __restrict__ km,
                                                     const float* __restrict__ query,
                                                     float* __restrict__ logits,
                                                     float* __restrict__ wtso,
                                                     float* __restrict__ vm,
                                                     float* __restrict__ att,
                                                     float* __restrict__ q1) {
  __shared__ unsigned short As[2 * 4096];
  __shared__ unsigned short Bs[128 * 136];
  __shared__ float lgS[8];
  __shared__ float wtsS[8];
  float* attL = (float*)As;
  int bid = blockIdx.x;
  int swz = (bid & 7) * 2048 + (bid >> 3);
  int b = swz;
  size_t m0 = (size_t)swz * 128;
  int tid = threadIdx.x;
  int wave = tid >> 6, lane = tid & 63;
  int wr = wave >> 1, wc = wave & 1;
  int r = tid >> 1, h = tid & 1;
  int la = lane & 15, lkq = lane >> 4;
  int sl = ((lkq ^ ((la >> 1) & 3))) * 8;

  if (ABF) {
#pragma unroll
    for (int q = 0; q < 8; ++q) {
      bf16x8 v = *(const bf16x8*)(WvT + (size_t)r * 128 + h * 64 + q * 8);
      *(bf16x8*)(Bs + r * 136 + h * 64 + q * 8) = v;
    }
  } else {
#pragma unroll
    for (int q = 0; q < 16; ++q) {
      int flat = q * 256 + tid;
      int k = flat >> 5;
      int n4 = (flat & 31) * 4;
      float4 v = *(const float4*)(Wv + (size_t)k * 128 + n4);
      Bs[(n4 + 0) * 136 + k] = f2bf(v.x);
      Bs[(n4 + 1) * 136 + k] = f2bf(v.y);
      Bs[(n4 + 2) * 136 + k] = f2bf(v.z);
      Bs[(n4 + 3) * 136 + k] = f2bf(v.w);
    }
  }

  const unsigned short *ap0 = nullptr, *ap1 = nullptr;
  int ldsA0 = wave * 1024, ldsA1 = ldsA0 + 512;
  if (ABF) {
    int p0 = wave * 128 + lane;
    int tr0 = p0 >> 2, ds0 = (p0 & 3) ^ ((tr0 >> 1) & 3);
    int p1 = p0 + 64;
    int tr1 = p1 >> 2, ds1 = (p1 & 3) ^ ((tr1 >> 1) & 3);
    ap0 = Abf + ((size_t)b * 8 + (tr0 >> 4)) * 2304 + 128 + (tr0 & 15) * 128 + ds0 * 8;
    ap1 = Abf + ((size_t)b * 8 + (tr1 >> 4)) * 2304 + 128 + (tr1 & 15) * 128 + ds1 * 8;
    __builtin_amdgcn_global_load_lds(
        (const __attribute__((address_space(1))) void*)(ap0),
        (__attribute__((address_space(3))) void*)(As + ldsA0), 16, 0, 0);
    __builtin_amdgcn_global_load_lds(
        (const __attribute__((address_space(1))) void*)(ap1),
        (__attribute__((address_space(3))) void*)(As + ldsA1), 16, 0, 0);
  }

  if (FATTN) {
    const float* qr = query + (size_t)b * 384;
#pragma unroll
    for (int i = 0; i < 2; ++i) {
      int n = wave * 2 + i;
      const float* kr = km + ((size_t)b * 8 + n) * 384;
      float p = 0.f;
#pragma unroll
      for (int j = 0; j < 6; ++j) p = fmaf(qr[lane + 64 * j], kr[lane + 64 * j], p);
      p = wave_sum(p);
      if (lane == 0) {
        float l = p * 0.08838834764831845f;  // 1/sqrt(128)
        l = (l == 0.0f) ? -1e9f : l;
        lgS[n] = l;
        logits[(size_t)b * 8 + n] = l;
      }
    }
  }

  f32x4 acc[4][4];
#pragma unroll
  for (int i = 0; i < 4; ++i)
#pragma unroll
    for (int j = 0; j < 4; ++j) acc[i][j] = (f32x4)(0.f);

  if (ABF || FATTN) __syncthreads();  // seals B ds_writes + A gload(0) + lgS

  if (FATTN) {
    if (tid < 8) {
      float m = lgS[0];
#pragma unroll
      for (int i = 1; i < 8; ++i) m = fmaxf(m, lgS[i]);
      float s = 0.f;
#pragma unroll
      for (int i = 0; i < 8; ++i) s += expf(lgS[i] - m);
      float w = expf(lgS[tid] - m) / s;
      wtsS[tid] = w;
      wtso[(size_t)b * 8 + tid] = w;
    }
  }

  int cur = 0;
  for (int ks = 0; ks < 4; ++ks) {
    int k0 = ks * 32;
    if (ABF) {
      if (ks < 3) {
        __builtin_amdgcn_global_load_lds(
            (const __attribute__((address_space(1))) void*)(ap0 + k0 + 32),
            (__attribute__((address_space(3))) void*)(As + (cur ^ 1) * 4096 + ldsA0), 16, 0, 0);
        __builtin_amdgcn_global_load_lds(
            (const __attribute__((address_space(1))) void*)(ap1 + k0 + 32),
            (__attribute__((address_space(3))) void*)(As + (cur ^ 1) * 4096 + ldsA1), 16, 0, 0);
      }
    } else {
      const float* ap = sf + (m0 + r) * 128 + k0 + h * 16;
      float4 v0 = *(const float4*)(ap);
      float4 v1 = *(const float4*)(ap + 4);
      float4 v2 = *(const float4*)(ap + 8);
      float4 v3 = *(const float4*)(ap + 12);
      ushort4 p0 = make_ushort4(f2bf(v0.x), f2bf(v0.y), f2bf(v0.z), f2bf(v0.w));
      ushort4 p1 = make_ushort4(f2bf(v1.x), f2bf(v1.y), f2bf(v1.z), f2bf(v1.w));
      ushort4 p2 = make_ushort4(f2bf(v2.x), f2bf(v2.y), f2bf(v2.z), f2bf(v2.w));
      ushort4 p3 = make_ushort4(f2bf(v3.x), f2bf(v3.y), f2bf(v3.z), f2bf(v3.w));
      *(ushort4*)(As + r * 40 + h * 16)      = p0;
      *(ushort4*)(As + r * 40 + h * 16 + 4)  = p1;
      *(ushort4*)(As + r * 40 + h * 16 + 8)  = p2;
      *(ushort4*)(As + r * 40 + h * 16 + 12) = p3;
      __syncthreads();
    }
    const unsigned short* aL = ABF ? (As + cur * 4096) : As;
    bf16x8 af[4], bfr[4];
#pragma unroll
    for (int mi = 0; mi < 4; ++mi) {
      int rowl = wr * 64 + mi * 16 + la;
      af[mi] = ABF ? *(const bf16x8*)(aL + rowl * 32 + sl)
                   : *(const bf16x8*)(aL + rowl * 40 + lkq * 8);
    }
#pragma unroll
    for (int ni = 0; ni < 4; ++ni)
      bfr[ni] = *(const bf16x8*)(Bs + (wc * 64 + ni * 16 + la) * 136 + k0 + lkq * 8);
#pragma unroll
    for (int mi = 0; mi < 4; ++mi)
#pragma unroll
      for (int ni = 0; ni < 4; ++ni)
        acc[mi][ni] = __builtin_amdgcn_mfma_f32_16x16x32_bf16(af[mi], bfr[ni], acc[mi][ni], 0, 0, 0);
    __syncthreads();
    cur ^= 1;
  }

  float w4[4];
#pragma unroll
  for (int mi = 0; mi < 4; ++mi)
    w4[mi] = FATTN ? wtsS[wr * 4 + mi] : wts[(size_t)b * 8 + wr * 4 + mi];
  float pacc[4][4];
#pragma unroll
  for (int ni = 0; ni < 4; ++ni)
#pragma unroll
    for (int j = 0; j < 4; ++j) pacc[ni][j] = 0.f;
#pragma unroll
  for (int mi = 0; mi < 4; ++mi) {
#pragma unroll
    for (int ni = 0; ni < 4; ++ni) {
      int colg = wc * 64 + ni * 16 + la;
      float bb = bv[colg];
#pragma unroll
      for (int j = 0; j < 4; ++j) {
        size_t rowg = m0 + wr * 64 + mi * 16 + lkq * 4 + j;
        float v = acc[mi][ni][j] + bb;
        vm[rowg * 128 + colg] = v;
        pacc[ni][j] = fmaf(w4[mi], v, pacc[ni][j]);
      }
    }
  }
  if (wr == 0) {
#pragma unroll
    for (int ni = 0; ni < 4; ++ni)
#pragma unroll
      for (int j = 0; j < 4; ++j)
        attL[(lkq * 4 + j) * 132 + wc * 64 + ni * 16 + la] = pacc[ni][j];
  }
  __syncthreads();
  if (wr == 1) {
#pragma unroll
    for (int ni = 0; ni < 4; ++ni)
#pragma unroll
      for (int j = 0; j < 4; ++j)
        attL[(lkq * 4 + j) * 132 + wc * 64 + ni * 16 + la] += pacc[ni][j];
  }
  __syncthreads();
#pragma unroll
  for (int i = 0; i < 2; ++i) {
    int fidx = tid + i * 256;
    int a = fidx >> 5, c = (fidx & 31) * 4;
    f32x4 vv = *(const f32x4*)(attL + a * 132 + c);
    *(f32x4*)(att + (size_t)b * 2048 + a * 128 + c) = vv;
  }
  for (int j = wave; j < 16; j += 4) {
    float p = task[(size_t)b * 1024 + lane] * attL[j * 132 + lane]
            + task[(size_t)b * 1024 + 64 + lane] * attL[j * 132 + 64 + lane];
    p = wave_sum(p);
    if (lane == 0) q1[(size_t)b * 16 + j] = p;
  }
}

extern "C" void kernel_launch(void* const* d_in, const int* in_sizes, int n_in,
                              void* d_out, int out_size, void* d_ws, size_t ws_size,
                              hipStream_t stream) {
  const float* basis = (const float*)d_in[0];
  const float* sf    = (const float*)d_in[1];
  const float* task  = (const float*)d_in[2];
  const float* mask  = (const float*)d_in[3];
  const float* Wq    = (const float*)d_in[4];
  const float* Wk    = (const float*)d_in[5];
  const float* bk    = (const float*)d_in[6];
  const float* Wv    = (const float*)d_in[7];
  const float* bv    = (const float*)d_in[8];

  float* out  = (float*)d_out;
  float* q1   = out;
  float* att  = out + OFF_ATT;
  float* logi = out + OFF_LOG;
  float* wts  = out + OFF_W;
  float* km   = out + OFF_KM;
  float* vm   = out + OFF_VM;
  float* simo = out + OFF_SIM;

  // d_ws layout (preferred path): Abf | WkT | WqT | WvT | query | invn = ~634MB.
  constexpr size_t WS_NEED = 603979776ull + 1769472ull + 1769472ull + 32768ull +
                             25165824ull + 524288ull;
  bool usews = ws_size >= WS_NEED;

  unsigned short *Abf, *WkT, *WqT, *WvT = nullptr;
  float *query, *invn;
  if (usews) {
    unsigned char* ws = (unsigned char*)d_ws;
    Abf   = (unsigned short*)ws;
    WkT   = (unsigned short*)(ws + 603979776ull);
    WqT   = (unsigned short*)(ws + 605749248ull);
    WvT   = (unsigned short*)(ws + 607518720ull);
    query = (float*)(ws + 607551488ull);
    invn  = (float*)(ws + 632717312ull);

    hipMemsetAsync(simo, 0, 7 * sizeof(float), stream);
    wprep3<<<436, 256, 0, stream>>>(Wk, Wq, Wv, WkT, WqT, WvT);
    abuild_sim_fn<<<16384, 576, 0, stream>>>(basis, sf, task, Abf, simo);
    // combined keys (3072 blocks) + query (384 blocks), counted-vmcnt 512-thr
    qk512<<<3456, 512, 0, stream>>>(Abf, WkT, WqT, bk, mask, km, query);
    // values GEMM + fused attn/softmax/attend/q1
    v_gemm_attend<1, 1><<<16384, 256, 0, stream>>>(sf, Abf, Wv, WvT, bv, nullptr,
                                                   task, km, query, logi, wts,
                                                   vm, att, q1);
  } else {
    // fallback: r11 pipeline with output-region stashes
    query = att;
    invn  = att + 6291456;
    WkT   = (unsigned short*)(att + 6422528);
    WqT   = WkT + 884736;
    Abf   = (unsigned short*)vm;

    norm_kernel<<<32768, 256, 0, stream>>>(task, invn, simo);
    wprep_t<<<216, 256, 0, stream>>>(Wk, WkT, 2304, 384);
    wprep_t<<<216, 256, 0, stream>>>(Wq, WqT, 2304, 384);
    abuild_sim<<<16384, 576, 0, stream>>>(basis, sf, task, invn, Abf, simo);
    qk2<<<3456, 256, 0, stream>>>(Abf, WkT, WqT, bk, mask, km, query);
    attn_kernel4<<<4096, 256, 0, stream>>>(query, km, logi, wts);
    v_gemm_attend<0, 0><<<16384, 256, 0, stream>>>(sf, nullptr, Wv, nullptr, bv, wts,
                                                   task, nullptr, nullptr, nullptr,
                                                   nullptr, vm, att, q1);
  }
}

// Round 14
// 1168.006 us; speedup vs baseline: 1.2923x; 1.0464x over previous
//
#include <hip/hip_runtime.h>
#include <hip/hip_bf16.h>
#include <math.h>

// B=16384, NB=8, NA=16, D=128, IN_DIM=2304, QK_DIM=384, V_DIM=128
static constexpr size_t OFF_ATT = 262144;      // attended_sf (33,554,432 f32)
static constexpr size_t OFF_LOG = 33816576;    // attn_logits
static constexpr size_t OFF_W   = 33947648;    // attention_weights
static constexpr size_t OFF_KM  = 34078720;    // keys_masked
static constexpr size_t OFF_VM  = 84410368;    // values_masked (268,435,456 f32)
static constexpr size_t OFF_SIM = 352845824;   // sim (7)

typedef short bf16x8 __attribute__((ext_vector_type(8)));
typedef float f32x4 __attribute__((ext_vector_type(4)));

__device__ inline unsigned short f2bf(float f) {
  union { float f; unsigned u; } x; x.f = f;
  unsigned r = x.u + 0x7FFFu + ((x.u >> 16) & 1u);  // RNE
  return (unsigned short)(r >> 16);
}

__device__ inline float wave_sum(float v) {
#pragma unroll
  for (int o = 32; o > 0; o >>= 1) v += __shfl_xor(v, o, 64);
  return v;
}

// FALLBACK only: one wave per (b,n) row inverse L2 norm + zero sim slots.
__global__ void norm_kernel(const float* __restrict__ task, float* __restrict__ invn,
                            float* __restrict__ simo) {
  int idx = blockIdx.x * 4 + (threadIdx.x >> 6);
  int lane = threadIdx.x & 63;
  float t0 = task[(size_t)idx * 128 + lane];
  float t1 = task[(size_t)idx * 128 + 64 + lane];
  float s = wave_sum(t0 * t0 + t1 * t1);
  if (lane == 0) invn[idx] = rsqrtf(s);
  if (blockIdx.x == 0 && threadIdx.x < 7) simo[threadIdx.x] = 0.0f;
}

// Tiled transpose+cvt for all three weights in one dispatch (436 blocks).
__global__ void wprep3(const float* __restrict__ Wk, const float* __restrict__ Wq,
                       const float* __restrict__ Wv,
                       unsigned short* __restrict__ WkT, unsigned short* __restrict__ WqT,
                       unsigned short* __restrict__ WvT) {
  int bb = blockIdx.x;
  const float* W; unsigned short* WT; int K, N, b2;
  if (bb < 216)      { W = Wk; WT = WkT; K = 2304; N = 384; b2 = bb; }
  else if (bb < 432) { W = Wq; WT = WqT; K = 2304; N = 384; b2 = bb - 216; }
  else               { W = Wv; WT = WvT; K = 128;  N = 128; b2 = bb - 432; }
  int ntn = N >> 6;
  int kt = b2 / ntn, nt = b2 % ntn;
  int k0 = kt * 64, n0 = nt * 64;
  __shared__ float t[64][65];
  int tid = threadIdx.x;
  int r = tid >> 2, c0 = (tid & 3) * 16;
#pragma unroll
  for (int q = 0; q < 4; ++q) {
    float4 v = *(const float4*)(W + (size_t)(k0 + r) * N + n0 + c0 + q * 4);
    t[r][c0 + q * 4 + 0] = v.x; t[r][c0 + q * 4 + 1] = v.y;
    t[r][c0 + q * 4 + 2] = v.z; t[r][c0 + q * 4 + 3] = v.w;
  }
  __syncthreads();
  int n = tid >> 2, kc0 = (tid & 3) * 16;
#pragma unroll
  for (int q = 0; q < 4; ++q) {
    int kc = kc0 + q * 4;
    ushort4 o = make_ushort4(f2bf(t[kc + 0][n]), f2bf(t[kc + 1][n]),
                             f2bf(t[kc + 2][n]), f2bf(t[kc + 3][n]));
    *(ushort4*)(WT + (size_t)(n0 + n) * K + k0 + kc) = o;
  }
}

// Legacy wprep (fallback path).
__global__ void wprep_t(const float* __restrict__ W, unsigned short* __restrict__ WT,
                        int K, int N) {
  int ntn = N >> 6;
  int kt = blockIdx.x / ntn, nt = blockIdx.x % ntn;
  int k0 = kt * 64, n0 = nt * 64;
  __shared__ float t[64][65];
  int tid = threadIdx.x;
  int r = tid >> 2, c0 = (tid & 3) * 16;
#pragma unroll
  for (int q = 0; q < 4; ++q) {
    float4 v = *(const float4*)(W + (size_t)(k0 + r) * N + n0 + c0 + q * 4);
    t[r][c0 + q * 4 + 0] = v.x; t[r][c0 + q * 4 + 1] = v.y;
    t[r][c0 + q * 4 + 2] = v.z; t[r][c0 + q * 4 + 3] = v.w;
  }
  __syncthreads();
  int n = tid >> 2, kc0 = (tid & 3) * 16;
#pragma unroll
  for (int q = 0; q < 4; ++q) {
    int kc = kc0 + q * 4;
    ushort4 o = make_ushort4(f2bf(t[kc + 0][n]), f2bf(t[kc + 1][n]),
                             f2bf(t[kc + 2][n]), f2bf(t[kc + 3][n]));
    *(ushort4*)(WT + (size_t)(n0 + n) * K + k0 + kc) = o;
  }
}

// One block (576 thr) per b with FUSED task-norm.
__global__ __launch_bounds__(576) void abuild_sim_fn(const float* __restrict__ basis,
                                                     const float* __restrict__ sf,
                                                     const float* __restrict__ task,
                                                     unsigned short* __restrict__ Abf,
                                                     float* __restrict__ simo) {
  int b = blockIdx.x;
  int f = threadIdx.x;  // 0..575
  size_t row0 = (size_t)b * 8;
  float4 v[8];
  if (f >= 544) {
    float ss[8];
#pragma unroll
    for (int n = 0; n < 8; ++n) {
      float4 x = *(const float4*)(task + (row0 + n) * 128 + (f - 544) * 4);
      v[n] = x;
      ss[n] = x.x * x.x + x.y * x.y + x.z * x.z + x.w * x.w;
    }
#pragma unroll
    for (int n = 0; n < 8; ++n) {
#pragma unroll
      for (int o = 16; o > 0; o >>= 1) ss[n] += __shfl_xor(ss[n], o, 64);
      float iv = rsqrtf(ss[n]);
      v[n].x *= iv; v[n].y *= iv; v[n].z *= iv; v[n].w *= iv;
    }
  } else if (f < 32) {
#pragma unroll
    for (int n = 0; n < 8; ++n) v[n] = *(const float4*)(basis + (row0 + n) * 128 + f * 4);
  } else {
#pragma unroll
    for (int n = 0; n < 8; ++n) v[n] = *(const float4*)(sf + (row0 + n) * 2048 + (f - 32) * 4);
  }
#pragma unroll
  for (int n = 0; n < 8; ++n) {
    ushort4 o = make_ushort4(f2bf(v[n].x), f2bf(v[n].y), f2bf(v[n].z), f2bf(v[n].w));
    *(ushort4*)(Abf + (row0 + n) * 2304 + f * 4) = o;
  }
  float s7[7];
#pragma unroll
  for (int n = 1; n < 8; ++n) {
    float dx = v[n].x - v[n - 1].x, dy = v[n].y - v[n - 1].y;
    float dz = v[n].z - v[n - 1].z, dw = v[n].w - v[n - 1].w;
    s7[n - 1] = dx * dx + dy * dy + dz * dz + dw * dw;
  }
  __shared__ float red[9][7];
  int wid = threadIdx.x >> 6, lane = threadIdx.x & 63;
#pragma unroll
  for (int i = 0; i < 7; ++i) {
    float p = wave_sum(s7[i]);
    if (lane == 0) red[wid][i] = p;
  }
  __syncthreads();
  if (threadIdx.x < 7) {
    float s = 0.f;
#pragma unroll
    for (int w = 0; w < 9; ++w) s += red[w][threadIdx.x];
    atomicAdd(&simo[threadIdx.x], expf(-0.5f * s) * (1.0f / 16384.0f));
  }
}

// FALLBACK abuild (invn-based).
__global__ __launch_bounds__(576) void abuild_sim(const float* __restrict__ basis,
                                                  const float* __restrict__ sf,
                                                  const float* __restrict__ task,
                                                  const float* __restrict__ invn,
                                                  unsigned short* __restrict__ Abf,
                                                  float* __restrict__ simo) {
  int b = blockIdx.x;
  int f = threadIdx.x;
  size_t row0 = (size_t)b * 8;
  float4 v[8];
#pragma unroll
  for (int n = 0; n < 8; ++n) {
    size_t row = row0 + n;
    float4 x;
    if (f < 32)       x = *(const float4*)(basis + row * 128 + f * 4);
    else if (f < 544) x = *(const float4*)(sf + row * 2048 + (f - 32) * 4);
    else {
      x = *(const float4*)(task + row * 128 + (f - 544) * 4);
      float s = invn[row];
      x.x *= s; x.y *= s; x.z *= s; x.w *= s;
    }
    v[n] = x;
    ushort4 o = make_ushort4(f2bf(x.x), f2bf(x.y), f2bf(x.z), f2bf(x.w));
    *(ushort4*)(Abf + row * 2304 + f * 4) = o;
  }
  float s7[7];
#pragma unroll
  for (int n = 1; n < 8; ++n) {
    float dx = v[n].x - v[n - 1].x, dy = v[n].y - v[n - 1].y;
    float dz = v[n].z - v[n - 1].z, dw = v[n].w - v[n - 1].w;
    s7[n - 1] = dx * dx + dy * dy + dz * dz + dw * dw;
  }
  __shared__ float red[9][7];
  int wid = threadIdx.x >> 6, lane = threadIdx.x & 63;
#pragma unroll
  for (int i = 0; i < 7; ++i) {
    float p = wave_sum(s7[i]);
    if (lane == 0) red[wid][i] = p;
  }
  __syncthreads();
  if (threadIdx.x < 7) {
    float s = 0.f;
#pragma unroll
    for (int w = 0; w < 9; ++w) s += red[w][threadIdx.x];
    atomicAdd(&simo[threadIdx.x], expf(-0.5f * s) * (1.0f / 16384.0f));
  }
}

// 256x128-tile keys+query GEMM: 512 thr / 8 waves as 4Mx2N (64x64 wave tiles ->
// 8 ds_read per 16 MFMA, the 0.5 reads/MFMA ratio), BK=32, TRIPLE-buffered
// 72KB DYNAMIC LDS, counted-vmcnt pipeline (stage distance 2, vmcnt(3)),
// XOR involution swizzle, setprio around the MFMA cluster (T5).
// blocks [0,1536) keys (M=131072, 512 mt x 3 nt); [1536,1728) query (64 mt x 3).
__global__ __launch_bounds__(512) void qk256(const unsigned short* __restrict__ Abf,
                                             const unsigned short* __restrict__ WkT,
                                             const unsigned short* __restrict__ WqT,
                                             const float* __restrict__ bias,
                                             const float* __restrict__ mask,
                                             float* __restrict__ km,
                                             float* __restrict__ query) {
  extern __shared__ unsigned short dyn[];
  unsigned short* As = dyn;            // 3 x 8192 elems ([256][32] bf16)
  unsigned short* Bs = dyn + 24576;    // 3 x 4096 elems ([128][32] bf16)
  int bid = blockIdx.x;
  bool isq = bid >= 1536;
  int mt, nt;
  const unsigned short* WT;
  float* outp;
  if (!isq) {
    int swz = (bid & 7) * 192 + (bid >> 3);
    mt = swz / 3; nt = swz - mt * 3;
    WT = WkT; outp = km;
  } else {
    int q = bid - 1536;
    int swz = (q & 7) * 24 + (q >> 3);
    mt = swz / 3; nt = swz - mt * 3;
    WT = WqT; outp = query;
  }
  int tid = threadIdx.x;
  int wave = tid >> 6, lane = tid & 63;
  int wr = wave >> 1, wc = wave & 1;   // 4M x 2N wave grid; wave tile 64x64
  int m0g = mt * 256, n0g = nt * 128;

  // staging: thread t owns A-chunks t and t+512, B-chunk t. chunk c -> row=c>>2,
  // source slot = (c&3) ^ ((row>>1)&3) (involution; read side applies same XOR).
  int rowA0 = tid >> 2;
  int kcA0 = (((tid & 3) ^ ((rowA0 >> 1) & 3))) * 8;
  int rowA1 = rowA0 + 128;
  int kcA1 = (((tid & 3) ^ ((rowA1 >> 1) & 3))) * 8;
  size_t gA0 = isq ? (size_t)(m0g + rowA0) * 8 : (size_t)(m0g + rowA0);
  size_t gA1 = isq ? (size_t)(m0g + rowA1) * 8 : (size_t)(m0g + rowA1);
  const unsigned short* agA0 = Abf + gA0 * 2304 + kcA0;
  const unsigned short* agA1 = Abf + gA1 * 2304 + kcA1;
  const unsigned short* bg   = WT + (size_t)(n0g + rowA0) * 2304 + kcA0;
  int ldsA0 = wave * 512;          // elems; wave-uniform (HW adds lane*16B)
  int ldsA1 = 4096 + wave * 512;
  int ldsB  = wave * 512;

#define STAGE(ks, buf)                                                                   \
  do {                                                                                   \
    int _k0 = (ks) * 32;                                                                 \
    __builtin_amdgcn_global_load_lds(                                                    \
        (const __attribute__((address_space(1))) void*)(agA0 + _k0),                     \
        (__attribute__((address_space(3))) void*)(As + (buf) * 8192 + ldsA0),            \
        16, 0, 0);                                                                       \
    __builtin_amdgcn_global_load_lds(                                                    \
        (const __attribute__((address_space(1))) void*)(agA1 + _k0),                     \
        (__attribute__((address_space(3))) void*)(As + (buf) * 8192 + ldsA1),            \
        16, 0, 0);                                                                       \
    __builtin_amdgcn_global_load_lds(                                                    \
        (const __attribute__((address_space(1))) void*)(bg + _k0),                       \
        (__attribute__((address_space(3))) void*)(Bs + (buf) * 4096 + ldsB),             \
        16, 0, 0);                                                                       \
  } while (0)

  f32x4 acc[4][4];
#pragma unroll
  for (int i = 0; i < 4; ++i)
#pragma unroll
    for (int j = 0; j < 4; ++j) acc[i][j] = (f32x4)(0.f);

  int la = lane & 15;
  int sl = (((lane >> 4) ^ ((la >> 1) & 3))) * 8;  // swizzled k-slot for reads

  // prologue: two stages in flight; publish stage(0) only
  STAGE(0, 0);
  STAGE(1, 1);
  asm volatile("s_waitcnt vmcnt(3)" ::: "memory");
  __builtin_amdgcn_s_barrier();
  asm volatile("" ::: "memory");

  int rd = 0, st = 2;
  for (int ks = 0; ks < 72; ++ks) {
    if (ks < 70) STAGE(ks + 2, st);  // writes buf read at ks-1 (sealed by barrier(ks-1))
    const unsigned short* aL = As + rd * 8192;
    const unsigned short* bL = Bs + rd * 4096;
    bf16x8 af[4], bf[4];
#pragma unroll
    for (int mi = 0; mi < 4; ++mi)
      af[mi] = *(const bf16x8*)(aL + (wr * 64 + mi * 16 + la) * 32 + sl);
#pragma unroll
    for (int ni = 0; ni < 4; ++ni)
      bf[ni] = *(const bf16x8*)(bL + (wc * 64 + ni * 16 + la) * 32 + sl);
    __builtin_amdgcn_s_setprio(1);
#pragma unroll
    for (int mi = 0; mi < 4; ++mi)
#pragma unroll
      for (int ni = 0; ni < 4; ++ni)
        acc[mi][ni] = __builtin_amdgcn_mfma_f32_16x16x32_bf16(af[mi], bf[ni], acc[mi][ni], 0, 0, 0);
    __builtin_amdgcn_s_setprio(0);
    // publish stage(ks+1): only stage(ks+2)'s 3 loads remain in flight
    if (ks < 70) asm volatile("s_waitcnt vmcnt(3)" ::: "memory");
    else         asm volatile("s_waitcnt vmcnt(0)" ::: "memory");
    __builtin_amdgcn_s_barrier();
    asm volatile("" ::: "memory");
    rd = (rd == 2) ? 0 : rd + 1;
    st = (st == 2) ? 0 : st + 1;
  }
#undef STAGE

  int rq = lane >> 4;
#pragma unroll
  for (int mi = 0; mi < 4; ++mi) {
#pragma unroll
    for (int ni = 0; ni < 4; ++ni) {
      int colg = n0g + wc * 64 + ni * 16 + la;
#pragma unroll
      for (int j = 0; j < 4; ++j) {
        int rowg = m0g + wr * 64 + mi * 16 + rq * 4 + j;
        float v = acc[mi][ni][j];
        if (!isq)
          v = (v + bias[colg]) * mask[(size_t)rowg * 128 + (unsigned)colg / 3u];
        outp[(size_t)rowg * 384 + colg] = v;
      }
    }
  }
}

// r13-proven fallback: 128x128, 8 waves (2Mx4N), 48KB static triple-buffer.
__global__ __launch_bounds__(512) void qk512(const unsigned short* __restrict__ Abf,
                                             const unsigned short* __restrict__ WkT,
                                             const unsigned short* __restrict__ WqT,
                                             const float* __restrict__ bias,
                                             const float* __restrict__ mask,
                                             float* __restrict__ km,
                                             float* __restrict__ query) {
  __shared__ unsigned short As[3 * 4096];
  __shared__ unsigned short Bs[3 * 4096];
  int bid = blockIdx.x;
  bool isq = bid >= 3072;
  int mt, nt;
  const unsigned short* WT;
  float* outp;
  if (!isq) {
    int swz = (bid & 7) * 384 + (bid >> 3);
    mt = swz / 3; nt = swz - mt * 3;
    WT = WkT; outp = km;
  } else {
    int q = bid - 3072;
    int swz = (q & 7) * 48 + (q >> 3);
    mt = swz / 3; nt = swz - mt * 3;
    WT = WqT; outp = query;
  }
  int tid = threadIdx.x;
  int wave = tid >> 6, lane = tid & 63;
  int wr = wave >> 2, wc = wave & 3;
  int m0g = mt * 128, n0g = nt * 128;

  int c = tid;
  int arow = c >> 2, akc = ((c & 3) ^ ((arow >> 1) & 3)) * 8;
  size_t ga = isq ? (size_t)(m0g + arow) * 8 : (size_t)(m0g + arow);
  const unsigned short* ag = Abf + ga * 2304 + akc;
  const unsigned short* bg = WT + (size_t)(n0g + arow) * 2304 + akc;
  int ldsoff = wave * 512;

#define STAGE(ks, buf)                                                                   \
  do {                                                                                   \
    int _k0 = (ks) * 32;                                                                 \
    __builtin_amdgcn_global_load_lds(                                                    \
        (const __attribute__((address_space(1))) void*)(ag + _k0),                       \
        (__attribute__((address_space(3))) void*)(As + (buf) * 4096 + ldsoff),           \
        16, 0, 0);                                                                       \
    __builtin_amdgcn_global_load_lds(                                                    \
        (const __attribute__((address_space(1))) void*)(bg + _k0),                       \
        (__attribute__((address_space(3))) void*)(Bs + (buf) * 4096 + ldsoff),           \
        16, 0, 0);                                                                       \
  } while (0)

  f32x4 acc[4][2];
#pragma unroll
  for (int i = 0; i < 4; ++i)
#pragma unroll
    for (int j = 0; j < 2; ++j) acc[i][j] = (f32x4)(0.f);

  int la = lane & 15;
  int sl = (((lane >> 4) ^ ((la >> 1) & 3))) * 8;

  STAGE(0, 0);
  STAGE(1, 1);
  asm volatile("s_waitcnt vmcnt(2)" ::: "memory");
  __builtin_amdgcn_s_barrier();
  asm volatile("" ::: "memory");

  int rd = 0, st = 2;
  for (int ks = 0; ks < 72; ++ks) {
    if (ks < 70) STAGE(ks + 2, st);
    const unsigned short* aL = As + rd * 4096;
    const unsigned short* bL = Bs + rd * 4096;
    bf16x8 af[4], bf[2];
#pragma unroll
    for (int mi = 0; mi < 4; ++mi)
      af[mi] = *(const bf16x8*)(aL + (wr * 64 + mi * 16 + la) * 32 + sl);
#pragma unroll
    for (int ni = 0; ni < 2; ++ni)
      bf[ni] = *(const bf16x8*)(bL + (wc * 32 + ni * 16 + la) * 32 + sl);
#pragma unroll
    for (int mi = 0; mi < 4; ++mi)
#pragma unroll
      for (int ni = 0; ni < 2; ++ni)
        acc[mi][ni] = __builtin_amdgcn_mfma_f32_16x16x32_bf16(af[mi], bf[ni], acc[mi][ni], 0, 0, 0);
    if (ks < 70) asm volatile("s_waitcnt vmcnt(2)" ::: "memory");
    else         asm volatile("s_waitcnt vmcnt(0)" ::: "memory");
    __builtin_amdgcn_s_barrier();
    asm volatile("" ::: "memory");
    rd = (rd == 2) ? 0 : rd + 1;
    st = (st == 2) ? 0 : st + 1;
  }
#undef STAGE

  int rq = lane >> 4;
#pragma unroll
  for (int mi = 0; mi < 4; ++mi) {
#pragma unroll
    for (int ni = 0; ni < 2; ++ni) {
      int colg = nt * 128 + wc * 32 + ni * 16 + la;
#pragma unroll
      for (int j = 0; j < 4; ++j) {
        int rowg = mt * 128 + wr * 64 + mi * 16 + rq * 4 + j;
        float v = acc[mi][ni][j];
        if (!isq)
          v = (v + bias[colg]) * mask[(size_t)rowg * 128 + (unsigned)colg / 3u];
        outp[(size_t)rowg * 384 + colg] = v;
      }
    }
  }
}

// FALLBACK qk2 (256 threads, r8 2-phase body).
__global__ __launch_bounds__(256) void qk2(const unsigned short* __restrict__ Abf,
                                           const unsigned short* __restrict__ WkT,
                                           const unsigned short* __restrict__ WqT,
                                           const float* __restrict__ bias,
                                           const float* __restrict__ mask,
                                           float* __restrict__ km,
                                           float* __restrict__ query) {
  __shared__ unsigned short As[2 * 4096];
  __shared__ unsigned short Bs[2 * 4096];
  int bid = blockIdx.x;
  bool isq = bid >= 3072;
  int mt, nt;
  const unsigned short* WT;
  float* outp;
  if (!isq) {
    int swz = (bid & 7) * 384 + (bid >> 3);
    mt = swz / 3; nt = swz - mt * 3;
    WT = WkT; outp = km;
  } else {
    int q = bid - 3072;
    int swz = (q & 7) * 48 + (q >> 3);
    mt = swz / 3; nt = swz - mt * 3;
    WT = WqT; outp = query;
  }
  int tid = threadIdx.x;
  int wave = tid >> 6, lane = tid & 63;
  int wr = wave >> 1, wc = wave & 1;
  int m0g = mt * 128, n0g = nt * 128;

  int c_lo = wave * 128 + lane;
  int row_q0 = c_lo >> 2, kc_q0 = ((c_lo & 3) ^ ((row_q0 >> 1) & 3)) * 8;
  int c_hi = c_lo + 64;
  int row_q1 = c_hi >> 2, kc_q1 = ((c_hi & 3) ^ ((row_q1 >> 1) & 3)) * 8;
  size_t ga_q0 = isq ? (size_t)(m0g + row_q0) * 8 : (size_t)(m0g + row_q0);
  size_t ga_q1 = isq ? (size_t)(m0g + row_q1) * 8 : (size_t)(m0g + row_q1);
  const unsigned short* ag0 = Abf + ga_q0 * 2304 + kc_q0;
  const unsigned short* ag1 = Abf + ga_q1 * 2304 + kc_q1;
  const unsigned short* bg0 = WT + (size_t)(n0g + row_q0) * 2304 + kc_q0;
  const unsigned short* bg1 = WT + (size_t)(n0g + row_q1) * 2304 + kc_q1;
  int ldsoff0 = wave * 1024;
  int ldsoff1 = ldsoff0 + 512;

#define STAGE(ks, cur)                                                                   \
  do {                                                                                   \
    int _k0 = (ks) * 32;                                                                 \
    unsigned short* _a = As + (cur) * 4096;                                              \
    unsigned short* _b = Bs + (cur) * 4096;                                              \
    __builtin_amdgcn_global_load_lds(                                                    \
        (const __attribute__((address_space(1))) void*)(ag0 + _k0),                      \
        (__attribute__((address_space(3))) void*)(_a + ldsoff0), 16, 0, 0);              \
    __builtin_amdgcn_global_load_lds(                                                    \
        (const __attribute__((address_space(1))) void*)(ag1 + _k0),                      \
        (__attribute__((address_space(3))) void*)(_a + ldsoff1), 16, 0, 0);              \
    __builtin_amdgcn_global_load_lds(                                                    \
        (const __attribute__((address_space(1))) void*)(bg0 + _k0),                      \
        (__attribute__((address_space(3))) void*)(_b + ldsoff0), 16, 0, 0);              \
    __builtin_amdgcn_global_load_lds(                                                    \
        (const __attribute__((address_space(1))) void*)(bg1 + _k0),                      \
        (__attribute__((address_space(3))) void*)(_b + ldsoff1), 16, 0, 0);              \
  } while (0)

  f32x4 acc[4][4];
#pragma unroll
  for (int i = 0; i < 4; ++i)
#pragma unroll
    for (int j = 0; j < 4; ++j) acc[i][j] = (f32x4)(0.f);

  int la = lane & 15;
  int sl = (((lane >> 4) ^ ((la >> 1) & 3))) * 8;

  STAGE(0, 0);
  __syncthreads();
  int cur = 0;
  for (int ks = 0; ks < 72; ++ks) {
    if (ks < 71) STAGE(ks + 1, cur ^ 1);
    const unsigned short* aL = As + cur * 4096;
    const unsigned short* bL = Bs + cur * 4096;
    bf16x8 af[4], bf[4];
#pragma unroll
    for (int mi = 0; mi < 4; ++mi)
      af[mi] = *(const bf16x8*)(aL + (wr * 64 + mi * 16 + la) * 32 + sl);
#pragma unroll
    for (int ni = 0; ni < 4; ++ni)
      bf[ni] = *(const bf16x8*)(bL + (wc * 64 + ni * 16 + la) * 32 + sl);
#pragma unroll
    for (int mi = 0; mi < 4; ++mi)
#pragma unroll
      for (int ni = 0; ni < 4; ++ni)
        acc[mi][ni] = __builtin_amdgcn_mfma_f32_16x16x32_bf16(af[mi], bf[ni], acc[mi][ni], 0, 0, 0);
    __syncthreads();
    cur ^= 1;
  }
#undef STAGE

  int rq = lane >> 4;
#pragma unroll
  for (int mi = 0; mi < 4; ++mi) {
#pragma unroll
    for (int ni = 0; ni < 4; ++ni) {
      int colg = nt * 128 + wc * 64 + ni * 16 + la;
#pragma unroll
      for (int j = 0; j < 4; ++j) {
        int rowg = mt * 128 + wr * 64 + mi * 16 + rq * 4 + j;
        float v = acc[mi][ni][j];
        if (!isq)
          v = (v + bias[colg]) * mask[(size_t)rowg * 128 + (unsigned)colg / 3u];
        outp[(size_t)rowg * 384 + colg] = v;
      }
    }
  }
}

// FALLBACK attn (4 b per block, one wave per b).
__global__ __launch_bounds__(256) void attn_kernel4(const float* __restrict__ query,
                                                    const float* __restrict__ km,
                                                    float* __restrict__ logits,
                                                    float* __restrict__ wts) {
  int w = threadIdx.x >> 6, lane = threadIdx.x & 63;
  int b = blockIdx.x * 4 + w;
  float q[6];
#pragma unroll
  for (int j = 0; j < 6; ++j) q[j] = query[(size_t)b * 384 + lane + 64 * j];
  float lg[8];
#pragma unroll
  for (int n = 0; n < 8; ++n) {
    const float* kr = km + ((size_t)b * 8 + n) * 384;
    float p = 0.f;
#pragma unroll
    for (int j = 0; j < 6; ++j) p = fmaf(q[j], kr[lane + 64 * j], p);
    p = wave_sum(p);
    float l = p * 0.08838834764831845f;
    lg[n] = (l == 0.0f) ? -1e9f : l;
  }
  float m = lg[0];
#pragma unroll
  for (int i = 1; i < 8; ++i) m = fmaxf(m, lg[i]);
  float ex[8], s = 0.f;
#pragma unroll
  for (int i = 0; i < 8; ++i) { ex[i] = expf(lg[i] - m); s += ex[i]; }
  float inv = 1.0f / s;
  if (lane < 8) {
    float lv = lg[0], ev = ex[0];
#pragma unroll
    for (int i = 1; i < 8; ++i)
      if (lane == i) { lv = lg[i]; ev = ex[i]; }
    logits[(size_t)b * 8 + lane] = lv;
    wts[(size_t)b * 8 + lane] = ev * inv;
  }
}

// Values GEMM + fused attn-softmax + attend + q1. One block = one b.
template <int ABF, int FATTN>
__global__ __launch_bounds__(256) void v_gemm_attend(const float* __restrict__ sf,
                                                     const unsigned short* __restrict__ Abf,
                                                     const float* __restrict__ Wv,
                                                     const unsigned short* __restrict__ WvT,
                                                     const float* __restrict__ bv,
                                                     const float* __restrict__ wts,
                                                     const float* __restrict__ task,
                                                     const float* __restrict__ km,
                                                     const float* __restrict__ query,
                                                     float* __restrict__ logits,
                                                     float* __restrict__ wtso,
                                                     float* __restrict__ vm,
                                                     float* __restrict__ att,
                                                     float* __restrict__ q1) {
  __shared__ unsigned short As[2 * 4096];
  __shared__ unsigned short Bs[128 * 136];
  __shared__ float lgS[8];
  __shared__ float wtsS[8];
  float* attL = (float*)As;
  int bid = blockIdx.x;
  int swz = (bid & 7) * 2048 + (bid >> 3);
  int b = swz;
  size_t m0 = (size_t)swz * 128;
  int tid = threadIdx.x;
  int wave = tid >> 6, lane = tid & 63;
  int wr = wave >> 1, wc = wave & 1;
  int r = tid >> 1, h = tid & 1;
  int la = lane & 15, lkq = lane >> 4;
  int sl = ((lkq ^ ((la >> 1) & 3))) * 8;

  if (ABF) {
#pragma unroll
    for (int q = 0; q < 8; ++q) {
      bf16x8 v = *(const bf16x8*)(WvT + (size_t)r * 128 + h * 64 + q * 8);
      *(bf16x8*)(Bs + r * 136 + h * 64 + q * 8) = v;
    }
  } else {
#pragma unroll
    for (int q = 0; q < 16; ++q) {
      int flat = q * 256 + tid;
      int k = flat >> 5;
      int n4 = (flat & 31) * 4;
      float4 v = *(const float4*)(Wv + (size_t)k * 128 + n4);
      Bs[(n4 + 0) * 136 + k] = f2bf(v.x);
      Bs[(n4 + 1) * 136 + k] = f2bf(v.y);
      Bs[(n4 + 2) * 136 + k] = f2bf(v.z);
      Bs[(n4 + 3) * 136 + k] = f2bf(v.w);
    }
  }

  const unsigned short *ap0 = nullptr, *ap1 = nullptr;
  int ldsA0 = wave * 1024, ldsA1 = ldsA0 + 512;
  if (ABF) {
    int p0 = wave * 128 + lane;
    int tr0 = p0 >> 2, ds0 = (p0 & 3) ^ ((tr0 >> 1) & 3);
    int p1 = p0 + 64;
    int tr1 = p1 >> 2, ds1 = (p1 & 3) ^ ((tr1 >> 1) & 3);
    ap0 = Abf + ((size_t)b * 8 + (tr0 >> 4)) * 2304 + 128 + (tr0 & 15) * 128 + ds0 * 8;
    ap1 = Abf + ((size_t)b * 8 + (tr1 >> 4)) * 2304 + 128 + (tr1 & 15) * 128 + ds1 * 8;
    __builtin_amdgcn_global_load_lds(
        (const __attribute__((address_space(1))) void*)(ap0),
        (__attribute__((address_space(3))) void*)(As + ldsA0), 16, 0, 0);
    __builtin_amdgcn_global_load_lds(
        (const __attribute__((address_space(1))) void*)(ap1),
        (__attribute__((address_space(3))) void*)(As + ldsA1), 16, 0, 0);
  }

  if (FATTN) {
    const float* qr = query + (size_t)b * 384;
#pragma unroll
    for (int i = 0; i < 2; ++i) {
      int n = wave * 2 + i;
      const float* kr = km + ((size_t)b * 8 + n) * 384;
      float p = 0.f;
#pragma unroll
      for (int j = 0; j < 6; ++j) p = fmaf(qr[lane + 64 * j], kr[lane + 64 * j], p);
      p = wave_sum(p);
      if (lane == 0) {
        float l = p * 0.08838834764831845f;  // 1/sqrt(128)
        l = (l == 0.0f) ? -1e9f : l;
        lgS[n] = l;
        logits[(size_t)b * 8 + n] = l;
      }
    }
  }

  f32x4 acc[4][4];
#pragma unroll
  for (int i = 0; i < 4; ++i)
#pragma unroll
    for (int j = 0; j < 4; ++j) acc[i][j] = (f32x4)(0.f);

  if (ABF || FATTN) __syncthreads();  // seals B ds_writes + A gload(0) + lgS

  if (FATTN) {
    if (tid < 8) {
      float m = lgS[0];
#pragma unroll
      for (int i = 1; i < 8; ++i) m = fmaxf(m, lgS[i]);
      float s = 0.f;
#pragma unroll
      for (int i = 0; i < 8; ++i) s += expf(lgS[i] - m);
      float w = expf(lgS[tid] - m) / s;
      wtsS[tid] = w;
      wtso[(size_t)b * 8 + tid] = w;
    }
  }

  int cur = 0;
  for (int ks = 0; ks < 4; ++ks) {
    int k0 = ks * 32;
    if (ABF) {
      if (ks < 3) {
        __builtin_amdgcn_global_load_lds(
            (const __attribute__((address_space(1))) void*)(ap0 + k0 + 32),
            (__attribute__((address_space(3))) void*)(As + (cur ^ 1) * 4096 + ldsA0), 16, 0, 0);
        __builtin_amdgcn_global_load_lds(
            (const __attribute__((address_space(1))) void*)(ap1 + k0 + 32),
            (__attribute__((address_space(3))) void*)(As + (cur ^ 1) * 4096 + ldsA1), 16, 0, 0);
      }
    } else {
      const float* ap = sf + (m0 + r) * 128 + k0 + h * 16;
      float4 v0 = *(const float4*)(ap);
      float4 v1 = *(const float4*)(ap + 4);
      float4 v2 = *(const float4*)(ap + 8);
      float4 v3 = *(const float4*)(ap + 12);
      ushort4 p0 = make_ushort4(f2bf(v0.x), f2bf(v0.y), f2bf(v0.z), f2bf(v0.w));
      ushort4 p1 = make_ushort4(f2bf(v1.x), f2bf(v1.y), f2bf(v1.z), f2bf(v1.w));
      ushort4 p2 = make_ushort4(f2bf(v2.x), f2bf(v2.y), f2bf(v2.z), f2bf(v2.w));
      ushort4 p3 = make_ushort4(f2bf(v3.x), f2bf(v3.y), f2bf(v3.z), f2bf(v3.w));
      *(ushort4*)(As + r * 40 + h * 16)      = p0;
      *(ushort4*)(As + r * 40 + h * 16 + 4)  = p1;
      *(ushort4*)(As + r * 40 + h * 16 + 8)  = p2;
      *(ushort4*)(As + r * 40 + h * 16 + 12) = p3;
      __syncthreads();
    }
    const unsigned short* aL = ABF ? (As + cur * 4096) : As;
    bf16x8 af[4], bfr[4];
#pragma unroll
    for (int mi = 0; mi < 4; ++mi) {
      int rowl = wr * 64 + mi * 16 + la;
      af[mi] = ABF ? *(const bf16x8*)(aL + rowl * 32 + sl)
                   : *(const bf16x8*)(aL + rowl * 40 + lkq * 8);
    }
#pragma unroll
    for (int ni = 0; ni < 4; ++ni)
      bfr[ni] = *(const bf16x8*)(Bs + (wc * 64 + ni * 16 + la) * 136 + k0 + lkq * 8);
#pragma unroll
    for (int mi = 0; mi < 4; ++mi)
#pragma unroll
      for (int ni = 0; ni < 4; ++ni)
        acc[mi][ni] = __builtin_amdgcn_mfma_f32_16x16x32_bf16(af[mi], bfr[ni], acc[mi][ni], 0, 0, 0);
    __syncthreads();
    cur ^= 1;
  }

  float w4[4];
#pragma unroll
  for (int mi = 0; mi < 4; ++mi)
    w4[mi] = FATTN ? wtsS[wr * 4 + mi] : wts[(size_t)b * 8 + wr * 4 + mi];
  float pacc[4][4];
#pragma unroll
  for (int ni = 0; ni < 4; ++ni)
#pragma unroll
    for (int j = 0; j < 4; ++j) pacc[ni][j] = 0.f;
#pragma unroll
  for (int mi = 0; mi < 4; ++mi) {
#pragma unroll
    for (int ni = 0; ni < 4; ++ni) {
      int colg = wc * 64 + ni * 16 + la;
      float bb = bv[colg];
#pragma unroll
      for (int j = 0; j < 4; ++j) {
        size_t rowg = m0 + wr * 64 + mi * 16 + lkq * 4 + j;
        float v = acc[mi][ni][j] + bb;
        vm[rowg * 128 + colg] = v;
        pacc[ni][j] = fmaf(w4[mi], v, pacc[ni][j]);
      }
    }
  }
  if (wr == 0) {
#pragma unroll
    for (int ni = 0; ni < 4; ++ni)
#pragma unroll
      for (int j = 0; j < 4; ++j)
        attL[(lkq * 4 + j) * 132 + wc * 64 + ni * 16 + la] = pacc[ni][j];
  }
  __syncthreads();
  if (wr == 1) {
#pragma unroll
    for (int ni = 0; ni < 4; ++ni)
#pragma unroll
      for (int j = 0; j < 4; ++j)
        attL[(lkq * 4 + j) * 132 + wc * 64 + ni * 16 + la] += pacc[ni][j];
  }
  __syncthreads();
#pragma unroll
  for (int i = 0; i < 2; ++i) {
    int fidx = tid + i * 256;
    int a = fidx >> 5, c = (fidx & 31) * 4;
    f32x4 vv = *(const f32x4*)(attL + a * 132 + c);
    *(f32x4*)(att + (size_t)b * 2048 + a * 128 + c) = vv;
  }
  for (int j = wave; j < 16; j += 4) {
    float p = task[(size_t)b * 1024 + lane] * attL[j * 132 + lane]
            + task[(size_t)b * 1024 + 64 + lane] * attL[j * 132 + 64 + lane];
    p = wave_sum(p);
    if (lane == 0) q1[(size_t)b * 16 + j] = p;
  }
}

extern "C" void kernel_launch(void* const* d_in, const int* in_sizes, int n_in,
                              void* d_out, int out_size, void* d_ws, size_t ws_size,
                              hipStream_t stream) {
  const float* basis = (const float*)d_in[0];
  const float* sf    = (const float*)d_in[1];
  const float* task  = (const float*)d_in[2];
  const float* mask  = (const float*)d_in[3];
  const float* Wq    = (const float*)d_in[4];
  const float* Wk    = (const float*)d_in[5];
  const float* bk    = (const float*)d_in[6];
  const float* Wv    = (const float*)d_in[7];
  const float* bv    = (const float*)d_in[8];

  float* out  = (float*)d_out;
  float* q1   = out;
  float* att  = out + OFF_ATT;
  float* logi = out + OFF_LOG;
  float* wts  = out + OFF_W;
  float* km   = out + OFF_KM;
  float* vm   = out + OFF_VM;
  float* simo = out + OFF_SIM;

  // d_ws layout (preferred path): Abf | WkT | WqT | WvT | query | invn = ~634MB.
  constexpr size_t WS_NEED = 603979776ull + 1769472ull + 1769472ull + 32768ull +
                             25165824ull + 524288ull;
  bool usews = ws_size >= WS_NEED;

  unsigned short *Abf, *WkT, *WqT, *WvT = nullptr;
  float *query, *invn;
  if (usews) {
    unsigned char* ws = (unsigned char*)d_ws;
    Abf   = (unsigned short*)ws;
    WkT   = (unsigned short*)(ws + 603979776ull);
    WqT   = (unsigned short*)(ws + 605749248ull);
    WvT   = (unsigned short*)(ws + 607518720ull);
    query = (float*)(ws + 607551488ull);
    invn  = (float*)(ws + 632717312ull);

    hipMemsetAsync(simo, 0, 7 * sizeof(float), stream);
    wprep3<<<436, 256, 0, stream>>>(Wk, Wq, Wv, WkT, WqT, WvT);
    abuild_sim_fn<<<16384, 576, 0, stream>>>(basis, sf, task, Abf, simo);
    // keys+query GEMM: 256x128 tile, 72KB dynamic-LDS counted-vmcnt (preferred);
    // fall back to the r13-proven 48KB qk512 if large dynamic LDS is unavailable.
    hipError_t aerr = hipFuncSetAttribute(
        reinterpret_cast<const void*>(qk256),
        hipFuncAttributeMaxDynamicSharedMemorySize, 73728);
    if (aerr == hipSuccess)
      qk256<<<1728, 512, 73728, stream>>>(Abf, WkT, WqT, bk, mask, km, query);
    else
      qk512<<<3456, 512, 0, stream>>>(Abf, WkT, WqT, bk, mask, km, query);
    // values GEMM + fused attn/softmax/attend/q1
    v_gemm_attend<1, 1><<<16384, 256, 0, stream>>>(sf, Abf, Wv, WvT, bv, nullptr,
                                                   task, km, query, logi, wts,
                                                   vm, att, q1);
  } else {
    // fallback: r11 pipeline with output-region stashes
    query = att;
    invn  = att + 6291456;
    WkT   = (unsigned short*)(att + 6422528);
    WqT   = WkT + 884736;
    Abf   = (unsigned short*)vm;

    norm_kernel<<<32768, 256, 0, stream>>>(task, invn, simo);
    wprep_t<<<216, 256, 0, stream>>>(Wk, WkT, 2304, 384);
    wprep_t<<<216, 256, 0, stream>>>(Wq, WqT, 2304, 384);
    abuild_sim<<<16384, 576, 0, stream>>>(basis, sf, task, invn, Abf, simo);
    qk2<<<3456, 256, 0, stream>>>(Abf, WkT, WqT, bk, mask, km, query);
    attn_kernel4<<<4096, 256, 0, stream>>>(query, km, logi, wts);
    v_gemm_attend<0, 0><<<16384, 256, 0, stream>>>(sf, nullptr, Wv, nullptr, bv, wts,
                                                   task, nullptr, nullptr, nullptr,
                                                   nullptr, vm, att, q1);
  }
}